// Round 1
// baseline (395.804 us; speedup 1.0000x reference)
//
#include <hip/hip_runtime.h>
#include <hip/hip_bf16.h>
#include <stdint.h>

// ---------------------------------------------------------------------------
// Co-Guiding GAT forward: 2 layers x 4 masked-MHA branches, B=4 N=1024 D=256
// H=8 dk=32.  bf16 MFMA for all GEMMs + fused flash-style masked attention.
// ---------------------------------------------------------------------------

using bf16x8 = __attribute__((ext_vector_type(8))) short;   // 8 bf16 (4 VGPRs)
using f32x4  = __attribute__((ext_vector_type(4))) float;   // 4 fp32 acc

#define DEVI __device__ __forceinline__

DEVI uint16_t f2bf(float x) {                 // RNE f32 -> bf16 bits
  uint32_t u = __float_as_uint(x);
  u += 0x7FFFu + ((u >> 16) & 1u);
  return (uint16_t)(u >> 16);
}
DEVI uint32_t pack2bf(float lo, float hi) {
  return (uint32_t)f2bf(lo) | ((uint32_t)f2bf(hi) << 16);
}

// ---------------------------------------------------------------------------
// Weight prep: W[k][n] fp32 -> Wt[n][k] bf16, for 4 types x 8 mats (L*4).
// out layout: [type][mat][256][256]
// ---------------------------------------------------------------------------
__global__ __launch_bounds__(256) void wprep_k(const float* __restrict__ Wq,
                                               const float* __restrict__ Wk,
                                               const float* __restrict__ Wv,
                                               const float* __restrict__ Wo,
                                               uint16_t* __restrict__ out) {
  const int z = blockIdx.z;
  const int type = z >> 3, mat = z & 7;
  const float* W = (type == 0 ? Wq : type == 1 ? Wk : type == 2 ? Wv : Wo)
                   + (size_t)mat * 65536;
  uint16_t* o = out + (size_t)type * 524288 + (size_t)mat * 65536;
  const int r0 = blockIdx.y * 64, c0 = blockIdx.x * 64;
  __shared__ float tl[64][68];
  const int t = threadIdx.x;
  {
    const int rr = t >> 2, cb = (t & 3) * 16;
    const float* src = W + (size_t)(r0 + rr) * 256 + c0 + cb;
    #pragma unroll
    for (int q = 0; q < 4; ++q) {
      float4 v = *(const float4*)(src + q * 4);
      tl[rr][cb + q*4 + 0] = v.x; tl[rr][cb + q*4 + 1] = v.y;
      tl[rr][cb + q*4 + 2] = v.z; tl[rr][cb + q*4 + 3] = v.w;
    }
  }
  __syncthreads();
  {
    const int nn = t >> 2, kb = (t & 3) * 16;
    __align__(16) uint16_t tmp[16];
    #pragma unroll
    for (int q = 0; q < 16; ++q) tmp[q] = f2bf(tl[kb + q][nn]);
    uint16_t* dst = o + (size_t)(c0 + nn) * 256 + r0 + kb;
    *(uint4*)&dst[0] = *(uint4*)&tmp[0];
    *(uint4*)&dst[8] = *(uint4*)&tmp[8];
  }
}

// ---------------------------------------------------------------------------
// Adjacency -> bitmask: adj[b][q][k] int32 -> bits[b][q][k/32] u32
// ---------------------------------------------------------------------------
struct AdjArgs { const int* adj[4]; uint32_t* bits[4]; };

__global__ __launch_bounds__(256) void adjbits_k(AdjArgs a) {
  const int* adj = a.adj[blockIdx.z];
  uint32_t* bits = a.bits[blockIdx.z];
  const size_t i = (size_t)blockIdx.x * 256 + threadIdx.x;
  const int lane = threadIdx.x & 63;
  const int v = adj[i];
  unsigned long long m = __ballot(v != 0);
  if ((lane & 31) == 0) bits[i >> 5] = (uint32_t)(m >> (lane & 32));
}

// ---------------------------------------------------------------------------
// GEMM: C[4096][256] = A[4096][256] @ W[256][256] + bias (+res).
// Wt is bf16 [n][k].  ABF: A is bf16, else fp32 (converted while staging).
// RESOUT: fp32 output with residual add; else bf16 output.
// 128x128 tile, 256 threads (4 waves of 64x64), mfma 16x16x32 bf16.
// ---------------------------------------------------------------------------
struct GemmArgs {
  const void*     A[12];
  const uint16_t* W[12];
  const float*    bias[12];
  const float*    res[12];
  void*           C[12];
};

template <int ABF, int RESOUT>
__global__ __launch_bounds__(256) void gemm_k(GemmArgs args) {
  const int z  = blockIdx.z;
  const int m0 = blockIdx.y * 128, n0 = blockIdx.x * 128;
  const uint16_t* Wt = args.W[z];
  __shared__ __align__(16) uint16_t As[128 * 32];
  __shared__ __align__(16) uint16_t Bs[128 * 32];
  const int t = threadIdx.x;
  const int lane = t & 63, wid = t >> 6;
  const int g = lane >> 4, c = lane & 15;
  const int wm = (wid >> 1) * 64, wn = (wid & 1) * 64;
  const int sr = t >> 1, sc = (t & 1) * 16;
  f32x4 acc[4][4] = {};

  for (int k0 = 0; k0 < 256; k0 += 32) {
    if (ABF) {
      const uint16_t* src = (const uint16_t*)args.A[z] + (size_t)(m0 + sr) * 256 + k0 + sc;
      *(uint4*)&As[sr * 32 + sc]     = *(const uint4*)src;
      *(uint4*)&As[sr * 32 + sc + 8] = *(const uint4*)(src + 8);
    } else {
      const float* src = (const float*)args.A[z] + (size_t)(m0 + sr) * 256 + k0 + sc;
      float4 f0 = *(const float4*)(src + 0),  f1 = *(const float4*)(src + 4);
      float4 f2 = *(const float4*)(src + 8),  f3 = *(const float4*)(src + 12);
      __align__(16) uint32_t pk[8] = {
        pack2bf(f0.x, f0.y), pack2bf(f0.z, f0.w), pack2bf(f1.x, f1.y), pack2bf(f1.z, f1.w),
        pack2bf(f2.x, f2.y), pack2bf(f2.z, f2.w), pack2bf(f3.x, f3.y), pack2bf(f3.z, f3.w) };
      *(uint4*)&As[sr * 32 + sc]     = *(uint4*)&pk[0];
      *(uint4*)&As[sr * 32 + sc + 8] = *(uint4*)&pk[4];
    }
    {
      const uint16_t* srcB = Wt + (size_t)(n0 + sr) * 256 + k0 + sc;
      *(uint4*)&Bs[sr * 32 + sc]     = *(const uint4*)srcB;
      *(uint4*)&Bs[sr * 32 + sc + 8] = *(const uint4*)(srcB + 8);
    }
    __syncthreads();
    bf16x8 af[4], bfr[4];
    #pragma unroll
    for (int mt = 0; mt < 4; ++mt) af[mt]  = *(const bf16x8*)&As[(wm + mt * 16 + c) * 32 + g * 8];
    #pragma unroll
    for (int nt = 0; nt < 4; ++nt) bfr[nt] = *(const bf16x8*)&Bs[(wn + nt * 16 + c) * 32 + g * 8];
    #pragma unroll
    for (int mt = 0; mt < 4; ++mt)
      #pragma unroll
      for (int nt = 0; nt < 4; ++nt)
        acc[mt][nt] = __builtin_amdgcn_mfma_f32_16x16x32_bf16(af[mt], bfr[nt], acc[mt][nt], 0, 0, 0);
    __syncthreads();
  }

  const float* bias = args.bias[z];
  float bv[4];
  #pragma unroll
  for (int nt = 0; nt < 4; ++nt) bv[nt] = bias[n0 + wn + nt * 16 + c];

  if (RESOUT) {
    const float* res = args.res[z];
    float* C = (float*)args.C[z];
    #pragma unroll
    for (int mt = 0; mt < 4; ++mt)
      #pragma unroll
      for (int r = 0; r < 4; ++r) {
        const int row = m0 + wm + mt * 16 + 4 * g + r;
        #pragma unroll
        for (int nt = 0; nt < 4; ++nt) {
          const int col = n0 + wn + nt * 16 + c;
          C[(size_t)row * 256 + col] = acc[mt][nt][r] + bv[nt] + res[(size_t)row * 256 + col];
        }
      }
  } else {
    uint16_t* C = (uint16_t*)args.C[z];
    #pragma unroll
    for (int mt = 0; mt < 4; ++mt)
      #pragma unroll
      for (int r = 0; r < 4; ++r) {
        const int row = m0 + wm + mt * 16 + 4 * g + r;
        #pragma unroll
        for (int nt = 0; nt < 4; ++nt) {
          const int col = n0 + wn + nt * 16 + c;
          C[(size_t)row * 256 + col] = f2bf(acc[mt][nt][r] + bv[nt]);
        }
      }
  }
}

// ---------------------------------------------------------------------------
// V transpose: V[b*1024+n][h*32+d] bf16 -> Vt[((b*8+h)*32+d)][n] bf16
// ---------------------------------------------------------------------------
struct VtArgs { const uint16_t* v[4]; uint16_t* vt[4]; };

__global__ __launch_bounds__(256) void vtrans_k(VtArgs args) {
  const int j = blockIdx.z;
  const int bh = blockIdx.y, b = bh >> 3, h = bh & 7;
  const int n0 = blockIdx.x * 64;
  __shared__ __align__(16) uint16_t tl[64][32];
  const int t = threadIdx.x;
  {
    const int n = t >> 2, d0 = (t & 3) * 8;
    *(uint4*)&tl[n][d0] =
      *(const uint4*)&args.v[j][(size_t)(b * 1024 + n0 + n) * 256 + h * 32 + d0];
  }
  __syncthreads();
  {
    const int d = t >> 3, nn = (t & 7) * 8;
    __align__(16) uint16_t tmp[8];
    #pragma unroll
    for (int q = 0; q < 8; ++q) tmp[q] = tl[nn + q][d];
    uint16_t* dst = args.vt[j] + ((size_t)(b * 8 + h) * 32 + d) * 1024 + n0 + nn;
    *(uint4*)dst = *(uint4*)tmp;
  }
}

// ---------------------------------------------------------------------------
// Fused masked flash attention.
// grid (16 q-tiles, 32 b*h, 4 branches), 256 threads = 4 independent waves,
// each wave owns 16 q rows.  Swapped QK^T: S^T tile = mfma(K_frag, Q_frag)
// -> lane (g,c) holds S[q=c][k=16t+4g+r]; lane-local online softmax;
// P -> bf16 via per-wave LDS; PV: O^T = mfma(Vt_frag, P_frag).
// ---------------------------------------------------------------------------
struct AttnArgs {
  const uint16_t* Q[4];
  const uint16_t* K[4];
  const uint16_t* Vt[4];
  const uint32_t* adjb[4];
  uint16_t*       O[4];
};

__global__ __launch_bounds__(256) void attn_k(AttnArgs args) {
  const int j  = blockIdx.z;
  const int bh = blockIdx.y, b = bh >> 3, h = bh & 7;
  const int q0 = blockIdx.x * 64;
  const int t = threadIdx.x, wid = t >> 6, lane = t & 63;
  const int g = lane >> 4, c = lane & 15;
  const int qrow = q0 + wid * 16 + c;

  const uint16_t* Q  = args.Q[j];
  const uint16_t* K  = args.K[j];
  const uint16_t* Vb = args.Vt[j] + (size_t)(b * 8 + h) * 32 * 1024;
  const uint32_t* adjrow = args.adjb[j] + (size_t)(b * 1024 + qrow) * 32;

  __shared__ __align__(16) uint16_t P[4][16][72];   // per-wave [q=c][k(64)+pad]

  const bf16x8 qf = *(const bf16x8*)&Q[(size_t)(b * 1024 + qrow) * 256 + h * 32 + g * 8];

  f32x4 oacc[2] = {};                 // O^T: lane reg r -> d = hh*16+4g+r, q=c
  float m = -3.0e38f, l = 0.f;
  const float scale = 0.17677669529663687f;   // 1/sqrt(32)
  f32x4 zf = {0.f, 0.f, 0.f, 0.f};

  for (int k0 = 0; k0 < 1024; k0 += 64) {
    const uint32_t w0 = adjrow[(k0 >> 5) + 0];
    const uint32_t w1 = adjrow[(k0 >> 5) + 1];

    f32x4 st[4];
    #pragma unroll
    for (int t4 = 0; t4 < 4; ++t4) {
      const bf16x8 kf =
        *(const bf16x8*)&K[(size_t)(b * 1024 + k0 + t4 * 16 + c) * 256 + h * 32 + g * 8];
      st[t4] = __builtin_amdgcn_mfma_f32_16x16x32_bf16(kf, qf, zf, 0, 0, 0);
    }

    float p[16];
    float tm = -3.0e38f;
    #pragma unroll
    for (int t4 = 0; t4 < 4; ++t4)
      #pragma unroll
      for (int r = 0; r < 4; ++r) {
        const int kk = t4 * 16 + 4 * g + r;
        const uint32_t w = (kk < 32) ? w0 : w1;
        const bool on = (w >> (kk & 31)) & 1u;
        const float s = on ? st[t4][r] * scale : -1.0e9f;
        p[t4 * 4 + r] = s;
        tm = fmaxf(tm, s);
      }
    tm = fmaxf(tm, __shfl_xor(tm, 16, 64));
    tm = fmaxf(tm, __shfl_xor(tm, 32, 64));
    const float mnew = fmaxf(m, tm);
    const float alpha = __expf(m - mnew);
    m = mnew;
    l *= alpha;
    float ls = 0.f;
    #pragma unroll
    for (int i = 0; i < 16; ++i) { p[i] = __expf(p[i] - mnew); ls += p[i]; }
    l += ls;
    #pragma unroll
    for (int r = 0; r < 4; ++r) { oacc[0][r] *= alpha; oacc[1][r] *= alpha; }

    // P -> bf16 LDS (row = this lane's q col c, k cols 16t+4g+{0..3})
    uint32_t* prow = (uint32_t*)&P[wid][c][0];
    #pragma unroll
    for (int t4 = 0; t4 < 4; ++t4) {
      prow[8 * t4 + 2 * g]     = pack2bf(p[t4 * 4 + 0], p[t4 * 4 + 1]);
      prow[8 * t4 + 2 * g + 1] = pack2bf(p[t4 * 4 + 2], p[t4 * 4 + 3]);
    }

    // PV: O^T += V^T @ P  (2 k-chunks x 2 d-halves)
    #pragma unroll
    for (int cc = 0; cc < 2; ++cc) {
      const bf16x8 pf = *(const bf16x8*)&P[wid][c][cc * 32 + g * 8];
      #pragma unroll
      for (int hh = 0; hh < 2; ++hh) {
        const bf16x8 vf =
          *(const bf16x8*)&Vb[(size_t)(hh * 16 + c) * 1024 + k0 + cc * 32 + g * 8];
        oacc[hh] = __builtin_amdgcn_mfma_f32_16x16x32_bf16(vf, pf, oacc[hh], 0, 0, 0);
      }
    }
  }

  l += __shfl_xor(l, 16, 64);
  l += __shfl_xor(l, 32, 64);
  const float inv = 1.0f / l;
  uint16_t* O = args.O[j];
  const size_t obase = (size_t)(b * 1024 + qrow) * 256 + h * 32;
  #pragma unroll
  for (int hh = 0; hh < 2; ++hh)
    #pragma unroll
    for (int r = 0; r < 4; ++r)
      O[obase + hh * 16 + 4 * g + r] = f2bf(oacc[hh][r] * inv);
}

// ---------------------------------------------------------------------------
// Fused LayerNorm(x0)+LayerNorm(x1) -> relu(sum) (+ optional input residual)
// One wave per row (256 cols, float4/lane).
// ---------------------------------------------------------------------------
struct LnArgs {
  const float* x0; const float* x1;
  const float* g0; const float* be0;
  const float* g1; const float* be1;
  const float* addin;   // null or original input (final layer)
  float* out;
};
struct LnBoth { LnArgs p[2]; };

__global__ __launch_bounds__(256) void ln_k(LnBoth args) {
  const LnArgs a = args.p[blockIdx.z];
  const int wid = threadIdx.x >> 6, lane = threadIdx.x & 63;
  const int row = blockIdx.x * 4 + wid;
  const size_t off = (size_t)row * 256 + lane * 4;

  const float4 x0 = *(const float4*)(a.x0 + off);
  const float4 x1 = *(const float4*)(a.x1 + off);
  float s0 = x0.x + x0.y + x0.z + x0.w;
  float s1 = x1.x + x1.y + x1.z + x1.w;
  #pragma unroll
  for (int s = 1; s < 64; s <<= 1) { s0 += __shfl_xor(s0, s, 64); s1 += __shfl_xor(s1, s, 64); }
  const float mu0 = s0 * (1.f / 256.f), mu1 = s1 * (1.f / 256.f);
  const float d0x = x0.x - mu0, d0y = x0.y - mu0, d0z = x0.z - mu0, d0w = x0.w - mu0;
  const float d1x = x1.x - mu1, d1y = x1.y - mu1, d1z = x1.z - mu1, d1w = x1.w - mu1;
  float v0 = d0x * d0x + d0y * d0y + d0z * d0z + d0w * d0w;
  float v1 = d1x * d1x + d1y * d1y + d1z * d1z + d1w * d1w;
  #pragma unroll
  for (int s = 1; s < 64; s <<= 1) { v0 += __shfl_xor(v0, s, 64); v1 += __shfl_xor(v1, s, 64); }
  const float r0 = rsqrtf(v0 * (1.f / 256.f) + 1e-5f);
  const float r1 = rsqrtf(v1 * (1.f / 256.f) + 1e-5f);

  const size_t po = (size_t)lane * 4;
  const float4 g0 = *(const float4*)(a.g0 + po), b0 = *(const float4*)(a.be0 + po);
  const float4 g1 = *(const float4*)(a.g1 + po), b1 = *(const float4*)(a.be1 + po);

  float4 y;
  y.x = fmaxf(d0x * r0 * g0.x + b0.x + d1x * r1 * g1.x + b1.x, 0.f);
  y.y = fmaxf(d0y * r0 * g0.y + b0.y + d1y * r1 * g1.y + b1.y, 0.f);
  y.z = fmaxf(d0z * r0 * g0.z + b0.z + d1z * r1 * g1.z + b1.z, 0.f);
  y.w = fmaxf(d0w * r0 * g0.w + b0.w + d1w * r1 * g1.w + b1.w, 0.f);
  if (a.addin) {
    const float4 ad = *(const float4*)(a.addin + off);
    y.x += ad.x; y.y += ad.y; y.z += ad.z; y.w += ad.w;
  }
  *(float4*)(a.out + off) = y;
}

// ---------------------------------------------------------------------------
// Host launch
// ---------------------------------------------------------------------------
extern "C" void kernel_launch(void* const* d_in, const int* in_sizes, int n_in,
                              void* d_out, int out_size, void* d_ws, size_t ws_size,
                              hipStream_t stream) {
  (void)in_sizes; (void)n_in; (void)out_size; (void)ws_size;
  const float* h_a = (const float*)d_in[0];
  const float* h_b = (const float*)d_in[1];
  const float* bq  = (const float*)d_in[7];
  const float* bk  = (const float*)d_in[9];
  const float* bv  = (const float*)d_in[11];
  const float* bo  = (const float*)d_in[13];
  const float* lng = (const float*)d_in[14];
  const float* lnb = (const float*)d_in[15];

  char* ws = (char*)d_ws;
  uint16_t* WT   = (uint16_t*)ws;                        // 4 MB: [type][mat][n][k] bf16
  uint32_t* ADJB = (uint32_t*)(ws + (4u  << 20));        // 2 MB: 4 x [b][q][32] u32
  float*    hA   = (float*)   (ws + (6u  << 20));        // 4 MB
  float*    hB   = (float*)   (ws + (10u << 20));        // 4 MB
  uint16_t* Qb[4]; uint16_t* Kb[4]; uint16_t* Vtb[4]; uint16_t* ATb[4]; float* MO[4];
  for (int j = 0; j < 4; ++j) {
    Qb[j]  = (uint16_t*)(ws + (14u << 20) + (size_t)j * (2u << 20));
    Kb[j]  = (uint16_t*)(ws + (22u << 20) + (size_t)j * (2u << 20));
    Vtb[j] = (uint16_t*)(ws + (30u << 20) + (size_t)j * (2u << 20));
    ATb[j] = (uint16_t*)(ws + (38u << 20) + (size_t)j * (2u << 20));
    MO[j]  = (float*)   (ws + (46u << 20) + (size_t)j * (4u << 20));
  }

  // prep: weights -> bf16 transposed; adj -> bitmasks
  wprep_k<<<dim3(4, 4, 32), 256, 0, stream>>>(
      (const float*)d_in[6], (const float*)d_in[8],
      (const float*)d_in[10], (const float*)d_in[12], WT);
  {
    AdjArgs aa;
    for (int j = 0; j < 4; ++j) {
      aa.adj[j]  = (const int*)d_in[2 + j];
      aa.bits[j] = ADJB + (size_t)j * 131072;
    }
    adjbits_k<<<dim3(16384, 1, 4), 256, 0, stream>>>(aa);
  }

  for (int i = 0; i < 2; ++i) {
    const float* inA = (i == 0) ? h_a : hA;
    const float* inB = (i == 0) ? h_b : hB;
    const float* qin[4]  = { inA, inB, inB, inA };   // a2a, b2b, a2b, b2a
    const float* kvin[4] = { inA, inB, inA, inB };

    // Q/K/V projections (12 GEMMs in one launch)
    {
      GemmArgs ga;
      for (int j = 0; j < 4; ++j) {
        const int mm = i * 4 + j;
        ga.A[j]     = qin[j];  ga.W[j]     = WT + 0 * 524288 + (size_t)mm * 65536;
        ga.bias[j]  = bq + mm * 256; ga.res[j] = nullptr; ga.C[j] = Qb[j];
        ga.A[4+j]   = kvin[j]; ga.W[4+j]   = WT + 1 * 524288 + (size_t)mm * 65536;
        ga.bias[4+j]= bk + mm * 256; ga.res[4+j] = nullptr; ga.C[4+j] = Kb[j];
        ga.A[8+j]   = kvin[j]; ga.W[8+j]   = WT + 2 * 524288 + (size_t)mm * 65536;
        ga.bias[8+j]= bv + mm * 256; ga.res[8+j] = nullptr; ga.C[8+j] = ATb[j]; // V temp
      }
      gemm_k<0, 0><<<dim3(2, 32, 12), 256, 0, stream>>>(ga);
    }
    // V -> Vt
    {
      VtArgs va;
      for (int j = 0; j < 4; ++j) { va.v[j] = ATb[j]; va.vt[j] = Vtb[j]; }
      vtrans_k<<<dim3(16, 32, 4), 256, 0, stream>>>(va);
    }
    // attention
    {
      AttnArgs at;
      for (int j = 0; j < 4; ++j) {
        at.Q[j] = Qb[j]; at.K[j] = Kb[j]; at.Vt[j] = Vtb[j];
        at.adjb[j] = ADJB + (size_t)j * 131072; at.O[j] = ATb[j];
      }
      attn_k<<<dim3(16, 32, 4), 256, 0, stream>>>(at);
    }
    // output projection + bias + residual (fp32)
    {
      GemmArgs go = {};
      for (int j = 0; j < 4; ++j) {
        const int mm = i * 4 + j;
        go.A[j] = ATb[j]; go.W[j] = WT + 3 * 524288 + (size_t)mm * 65536;
        go.bias[j] = bo + mm * 256; go.res[j] = qin[j]; go.C[j] = MO[j];
      }
      gemm_k<1, 1><<<dim3(2, 32, 4), 256, 0, stream>>>(go);
    }
    // LN + LN + relu-combine (+ final input residual)
    {
      LnBoth lb;
      float* outA = (i == 1) ? (float*)d_out : hA;
      float* outB = (i == 1) ? ((float*)d_out + 1048576) : hB;
      const float* addA = (i == 1) ? h_a : nullptr;
      const float* addB = (i == 1) ? h_b : nullptr;
      lb.p[0] = { MO[0], MO[3],
                  lng + (i * 4 + 0) * 256, lnb + (i * 4 + 0) * 256,
                  lng + (i * 4 + 3) * 256, lnb + (i * 4 + 3) * 256,
                  addA, outA };
      lb.p[1] = { MO[1], MO[2],
                  lng + (i * 4 + 1) * 256, lnb + (i * 4 + 1) * 256,
                  lng + (i * 4 + 2) * 256, lnb + (i * 4 + 2) * 256,
                  addB, outB };
      ln_k<<<dim3(1024, 1, 2), 256, 0, stream>>>(lb);
    }
  }
}

// Round 4
// 294.454 us; speedup vs baseline: 1.3442x; 1.3442x over previous
//
#include <hip/hip_runtime.h>
#include <hip/hip_bf16.h>
#include <stdint.h>

// ---------------------------------------------------------------------------
// Co-Guiding GAT forward: 2 layers x 4 masked-MHA branches, B=4 N=1024 D=256
// H=8 dk=32.  bf16 MFMA GEMMs + fused flash attention (32x32 MFMA, in-register
// softmax).  Round 4: R3 structure with ALL inline asm removed — cross-half
// exchange via __shfl_xor(.,32), bf16 pack via RNE bit-twiddle.  Isolates the
// permlane32_swap / cvt_pk_bf16 idioms as the suspected R2/R3 regression.
// ---------------------------------------------------------------------------

using bf16x8 = __attribute__((ext_vector_type(8))) short;   // 8 bf16 (4 VGPRs)
using f32x4  = __attribute__((ext_vector_type(4))) float;
using f32x16 = __attribute__((ext_vector_type(16))) float;

#define DEVI __device__ __forceinline__

DEVI uint16_t f2bf(float x) {                 // RNE f32 -> bf16 bits
  uint32_t u = __float_as_uint(x);
  u += 0x7FFFu + ((u >> 16) & 1u);
  return (uint16_t)(u >> 16);
}
DEVI uint32_t pack2bf(float lo, float hi) {
  return (uint32_t)f2bf(lo) | ((uint32_t)f2bf(hi) << 16);
}

// ---------------------------------------------------------------------------
// Weight prep: W[k][n] fp32 -> Wt[n][k] bf16, for 4 types x 8 mats (L*4).
// ---------------------------------------------------------------------------
__global__ __launch_bounds__(256) void wprep_k(const float* __restrict__ Wq,
                                               const float* __restrict__ Wk,
                                               const float* __restrict__ Wv,
                                               const float* __restrict__ Wo,
                                               uint16_t* __restrict__ out) {
  const int z = blockIdx.z;
  const int type = z >> 3, mat = z & 7;
  const float* W = (type == 0 ? Wq : type == 1 ? Wk : type == 2 ? Wv : Wo)
                   + (size_t)mat * 65536;
  uint16_t* o = out + (size_t)type * 524288 + (size_t)mat * 65536;
  const int r0 = blockIdx.y * 64, c0 = blockIdx.x * 64;
  __shared__ float tl[64][68];
  const int t = threadIdx.x;
  {
    const int rr = t >> 2, cb = (t & 3) * 16;
    const float* src = W + (size_t)(r0 + rr) * 256 + c0 + cb;
    #pragma unroll
    for (int q = 0; q < 4; ++q) {
      float4 v = *(const float4*)(src + q * 4);
      tl[rr][cb + q*4 + 0] = v.x; tl[rr][cb + q*4 + 1] = v.y;
      tl[rr][cb + q*4 + 2] = v.z; tl[rr][cb + q*4 + 3] = v.w;
    }
  }
  __syncthreads();
  {
    const int nn = t >> 2, kb = (t & 3) * 16;
    __align__(16) uint16_t tmp[16];
    #pragma unroll
    for (int q = 0; q < 16; ++q) tmp[q] = f2bf(tl[kb + q][nn]);
    uint16_t* dst = o + (size_t)(c0 + nn) * 256 + r0 + kb;
    *(uint4*)&dst[0] = *(uint4*)&tmp[0];
    *(uint4*)&dst[8] = *(uint4*)&tmp[8];
  }
}

// ---------------------------------------------------------------------------
// Adjacency -> TRANSPOSED bitmask: adj[b][q][k] -> bits[b][kw][q] (kw = k/32)
// ---------------------------------------------------------------------------
struct AdjArgs { const int* adj[4]; uint32_t* bits[4]; };

__global__ __launch_bounds__(256) void adjbits_k(AdjArgs a) {
  const int* adj = a.adj[blockIdx.z];
  uint32_t* bits = a.bits[blockIdx.z];
  const size_t i = (size_t)blockIdx.x * 256 + threadIdx.x;
  const int lane = threadIdx.x & 63;
  const int v = adj[i];
  unsigned long long m = __ballot(v != 0);
  if ((lane & 31) == 0) {
    const uint32_t wi = (uint32_t)(i >> 5);      // (b*1024+q)*32 + kw
    const uint32_t kw = wi & 31;
    const uint32_t q  = (wi >> 5) & 1023;
    const uint32_t bb = wi >> 15;
    bits[((bb * 32 + kw) << 10) | q] = (uint32_t)(m >> (lane & 32));
  }
}

// ---------------------------------------------------------------------------
// GEMM: C[4096][256] = (A[4096][256] @ W[256][256] + bias) * os (+res).
// ---------------------------------------------------------------------------
struct GemmArgs {
  const void*     A[12];
  const uint16_t* W[12];
  const float*    bias[12];
  const float*    res[12];
  void*           C[12];
  float           os[12];
};

template <int ABF, int RESOUT>
__global__ __launch_bounds__(256) void gemm_k(GemmArgs args) {
  const int z  = blockIdx.z;
  const int m0 = blockIdx.y * 128, n0 = blockIdx.x * 128;
  const uint16_t* Wt = args.W[z];
  __shared__ __align__(16) uint16_t As[128 * 32];
  __shared__ __align__(16) uint16_t Bs[128 * 32];
  const int t = threadIdx.x;
  const int lane = t & 63, wid = t >> 6;
  const int g = lane >> 4, c = lane & 15;
  const int wm = (wid >> 1) * 64, wn = (wid & 1) * 64;
  const int sr = t >> 1, sc = (t & 1) * 16;
  f32x4 acc[4][4] = {};

  for (int k0 = 0; k0 < 256; k0 += 32) {
    if (ABF) {
      const uint16_t* src = (const uint16_t*)args.A[z] + (size_t)(m0 + sr) * 256 + k0 + sc;
      *(uint4*)&As[sr * 32 + sc]     = *(const uint4*)src;
      *(uint4*)&As[sr * 32 + sc + 8] = *(const uint4*)(src + 8);
    } else {
      const float* src = (const float*)args.A[z] + (size_t)(m0 + sr) * 256 + k0 + sc;
      float4 f0 = *(const float4*)(src + 0),  f1 = *(const float4*)(src + 4);
      float4 f2 = *(const float4*)(src + 8),  f3 = *(const float4*)(src + 12);
      __align__(16) uint32_t pk[8] = {
        pack2bf(f0.x, f0.y), pack2bf(f0.z, f0.w), pack2bf(f1.x, f1.y), pack2bf(f1.z, f1.w),
        pack2bf(f2.x, f2.y), pack2bf(f2.z, f2.w), pack2bf(f3.x, f3.y), pack2bf(f3.z, f3.w) };
      *(uint4*)&As[sr * 32 + sc]     = *(uint4*)&pk[0];
      *(uint4*)&As[sr * 32 + sc + 8] = *(uint4*)&pk[4];
    }
    {
      const uint16_t* srcB = Wt + (size_t)(n0 + sr) * 256 + k0 + sc;
      *(uint4*)&Bs[sr * 32 + sc]     = *(const uint4*)srcB;
      *(uint4*)&Bs[sr * 32 + sc + 8] = *(const uint4*)(srcB + 8);
    }
    __syncthreads();
    bf16x8 af[4], bfr[4];
    #pragma unroll
    for (int mt = 0; mt < 4; ++mt) af[mt]  = *(const bf16x8*)&As[(wm + mt * 16 + c) * 32 + g * 8];
    #pragma unroll
    for (int nt = 0; nt < 4; ++nt) bfr[nt] = *(const bf16x8*)&Bs[(wn + nt * 16 + c) * 32 + g * 8];
    #pragma unroll
    for (int mt = 0; mt < 4; ++mt)
      #pragma unroll
      for (int nt = 0; nt < 4; ++nt)
        acc[mt][nt] = __builtin_amdgcn_mfma_f32_16x16x32_bf16(af[mt], bfr[nt], acc[mt][nt], 0, 0, 0);
    __syncthreads();
  }

  const float* bias = args.bias[z];
  const float osz = args.os[z];
  float bv[4];
  #pragma unroll
  for (int nt = 0; nt < 4; ++nt) bv[nt] = bias[n0 + wn + nt * 16 + c];

  if (RESOUT) {
    const float* res = args.res[z];
    float* C = (float*)args.C[z];
    #pragma unroll
    for (int mt = 0; mt < 4; ++mt)
      #pragma unroll
      for (int r = 0; r < 4; ++r) {
        const int row = m0 + wm + mt * 16 + 4 * g + r;
        #pragma unroll
        for (int nt = 0; nt < 4; ++nt) {
          const int col = n0 + wn + nt * 16 + c;
          C[(size_t)row * 256 + col] = (acc[mt][nt][r] + bv[nt]) * osz + res[(size_t)row * 256 + col];
        }
      }
  } else {
    uint16_t* C = (uint16_t*)args.C[z];
    #pragma unroll
    for (int mt = 0; mt < 4; ++mt)
      #pragma unroll
      for (int r = 0; r < 4; ++r) {
        const int row = m0 + wm + mt * 16 + 4 * g + r;
        #pragma unroll
        for (int nt = 0; nt < 4; ++nt) {
          const int col = n0 + wn + nt * 16 + c;
          C[(size_t)row * 256 + col] = f2bf((acc[mt][nt][r] + bv[nt]) * osz);
        }
      }
  }
}

// ---------------------------------------------------------------------------
// V transpose: V[b*1024+n][h*32+d] bf16 -> Vt[((b*8+h)*32+d)][n] bf16
// ---------------------------------------------------------------------------
struct VtArgs { const uint16_t* v[4]; uint16_t* vt[4]; };

__global__ __launch_bounds__(256) void vtrans_k(VtArgs args) {
  const int j = blockIdx.z;
  const int bh = blockIdx.y, b = bh >> 3, h = bh & 7;
  const int n0 = blockIdx.x * 64;
  __shared__ __align__(16) uint16_t tl[64][32];
  const int t = threadIdx.x;
  {
    const int n = t >> 2, d0 = (t & 3) * 8;
    *(uint4*)&tl[n][d0] =
      *(const uint4*)&args.v[j][(size_t)(b * 1024 + n0 + n) * 256 + h * 32 + d0];
  }
  __syncthreads();
  {
    const int d = t >> 3, nn = (t & 7) * 8;
    __align__(16) uint16_t tmp[8];
    #pragma unroll
    for (int q = 0; q < 8; ++q) tmp[q] = tl[nn + q][d];
    uint16_t* dst = args.vt[j] + ((size_t)(b * 8 + h) * 32 + d) * 1024 + n0 + nn;
    *(uint4*)dst = *(uint4*)tmp;
  }
}

// ---------------------------------------------------------------------------
// Fused masked flash attention, 32x32 MFMA, zero LDS, no inline asm.
// Lane (c=lane&31, hi=lane>>5) owns q-row c's softmax state; S^T = mfma(K,Q)
// gives lane reg r = S[q=c][kk=(r&3)+8*(r>>2)+4*hi].  Mask-before-max, fresh
// online rescale.  P -> bf16 (RNE) + cross-half exchange via __shfl_xor(.,32)
// + select builds the PV B-fragment in registers.
// ---------------------------------------------------------------------------
struct AttnArgs {
  const uint16_t* Q[4];
  const uint16_t* K[4];
  const uint16_t* Vt[4];
  const uint32_t* adjb[4];   // transposed [b][kw][q]
  uint16_t*       O[4];
};

__global__ __launch_bounds__(256) void attn_k(AttnArgs args) {
  const int bid = blockIdx.x;
  const int qt  = bid >> 7;           // 8 q-tiles per group
  const int grp = bid & 127;          // (branch,b,h) group -> same XCD
  const int bh = grp & 31, j = grp >> 5;
  const int b = bh >> 3, h = bh & 7;
  const int t = threadIdx.x, wid = t >> 6, lane = t & 63;
  const int c = lane & 31, hi = lane >> 5;
  const int qrow = qt * 128 + wid * 32 + c;

  const uint16_t* Q  = args.Q[j];
  const uint16_t* Kp = args.K[j] + (size_t)(b * 1024) * 256 + h * 32 + hi * 8;
  const uint16_t* Vp = args.Vt[j] + ((size_t)(b * 8 + h) * 32 + c) * 1024 + hi * 8;
  const uint32_t* adjT = args.adjb[j] + (size_t)b * 32768 + qrow;

  const size_t qoff = (size_t)(b * 1024 + qrow) * 256 + h * 32 + hi * 8;
  const bf16x8 qf0 = *(const bf16x8*)&Q[qoff];
  const bf16x8 qf1 = *(const bf16x8*)&Q[qoff + 16];

  f32x16 oacc = {};
  float m = -3.0e38f, l = 0.f;

  for (int k0 = 0; k0 < 1024; k0 += 32) {
    const uint32_t w = adjT[(size_t)(k0 >> 5) << 10] >> (hi * 4);
    const uint16_t* kr = Kp + (size_t)(k0 + c) * 256;
    const bf16x8 kf0 = *(const bf16x8*)kr;
    const bf16x8 kf1 = *(const bf16x8*)(kr + 16);
    const bf16x8 vf0 = *(const bf16x8*)(Vp + k0);        // issued early;
    const bf16x8 vf1 = *(const bf16x8*)(Vp + k0 + 16);   // used post-softmax

    f32x16 st = {};
    st = __builtin_amdgcn_mfma_f32_32x32x16_bf16(kf0, qf0, st, 0, 0, 0);
    st = __builtin_amdgcn_mfma_f32_32x32x16_bf16(kf1, qf1, st, 0, 0, 0);

    // mask BEFORE max (reference semantics): masked -> -1e9
    #pragma unroll
    for (int r = 0; r < 16; ++r) {
      const int pos = (r & 3) + 8 * (r >> 2);   // bit pos (w pre-shifted by 4*hi)
      st[r] = ((w >> pos) & 1u) ? st[r] : -1.0e9f;
    }

    float a0 = fmaxf(fmaxf(st[0],  st[1]),  fmaxf(st[2],  st[3]));
    float a1 = fmaxf(fmaxf(st[4],  st[5]),  fmaxf(st[6],  st[7]));
    float a2 = fmaxf(fmaxf(st[8],  st[9]),  fmaxf(st[10], st[11]));
    float a3 = fmaxf(fmaxf(st[12], st[13]), fmaxf(st[14], st[15]));
    float tm = fmaxf(fmaxf(a0, a1), fmaxf(a2, a3));
    tm = fmaxf(tm, __shfl_xor(tm, 32, 64));     // cross-half pair max

    // unconditional online rescale
    const float mn = fmaxf(m, tm);
    const float al = __builtin_exp2f(m - mn);
    m = mn; l *= al;
    #pragma unroll
    for (int r = 0; r < 16; ++r) oacc[r] *= al;

    float s0 = 0.f, s1 = 0.f, s2 = 0.f, s3 = 0.f;
    #pragma unroll
    for (int r = 0; r < 16; ++r) {
      const float pv = __builtin_exp2f(st[r] - m);   // masked: exp2(-1e9-m)=0
      st[r] = pv;
      if ((r & 3) == 0) s0 += pv; else if ((r & 3) == 1) s1 += pv;
      else if ((r & 3) == 2) s2 += pv; else s3 += pv;
    }
    l += (s0 + s1) + (s2 + s3);

    // pack to bf16 (RNE): u_i = (kk pair) per this lane's hi
    const uint32_t u0 = pack2bf(st[0],  st[1]),  u1 = pack2bf(st[2],  st[3]);
    const uint32_t u2 = pack2bf(st[4],  st[5]),  u3 = pack2bf(st[6],  st[7]);
    const uint32_t u4 = pack2bf(st[8],  st[9]),  u5 = pack2bf(st[10], st[11]);
    const uint32_t u6 = pack2bf(st[12], st[13]), u7 = pack2bf(st[14], st[15]);

    // cross-half exchange (shfl, convention-independent):
    // chunk0 frag words (kk = 8*hi + {0..7}):
    //   hi=0: [u0, u1, partner.u0, partner.u1]   (partner = lane^32, hi=1)
    //   hi=1: [partner.u2, partner.u3, u2, u3]
    const uint32_t p0s = (uint32_t)__shfl_xor((int)u0, 32, 64);
    const uint32_t p1s = (uint32_t)__shfl_xor((int)u1, 32, 64);
    const uint32_t p2s = (uint32_t)__shfl_xor((int)u2, 32, 64);
    const uint32_t p3s = (uint32_t)__shfl_xor((int)u3, 32, 64);
    const uint32_t p4s = (uint32_t)__shfl_xor((int)u4, 32, 64);
    const uint32_t p5s = (uint32_t)__shfl_xor((int)u5, 32, 64);
    const uint32_t p6s = (uint32_t)__shfl_xor((int)u6, 32, 64);
    const uint32_t p7s = (uint32_t)__shfl_xor((int)u7, 32, 64);

    union PU { uint32_t u[4]; bf16x8 v; };
    PU p0, p1;
    p0.u[0] = hi ? p2s : u0;  p0.u[1] = hi ? p3s : u1;
    p0.u[2] = hi ? u2  : p0s; p0.u[3] = hi ? u3  : p1s;
    p1.u[0] = hi ? p6s : u4;  p1.u[1] = hi ? p7s : u5;
    p1.u[2] = hi ? u6  : p4s; p1.u[3] = hi ? u7  : p5s;

    oacc = __builtin_amdgcn_mfma_f32_32x32x16_bf16(vf0, p0.v, oacc, 0, 0, 0);
    oacc = __builtin_amdgcn_mfma_f32_32x32x16_bf16(vf1, p1.v, oacc, 0, 0, 0);
  }

  l += __shfl_xor(l, 32, 64);
  const float inv = 1.0f / l;
  uint16_t* O = args.O[j];
  const size_t ob = (size_t)(b * 1024 + qrow) * 256 + h * 32 + 4 * hi;
  #pragma unroll
  for (int rq = 0; rq < 4; ++rq) {
    uint2 val;
    val.x = pack2bf(oacc[4*rq+0] * inv, oacc[4*rq+1] * inv);
    val.y = pack2bf(oacc[4*rq+2] * inv, oacc[4*rq+3] * inv);
    *(uint2*)&O[ob + 8 * rq] = val;
  }
}

// ---------------------------------------------------------------------------
// Fused LayerNorm(x0)+LayerNorm(x1) -> relu(sum) (+ optional input residual)
// ---------------------------------------------------------------------------
struct LnArgs {
  const float* x0; const float* x1;
  const float* g0; const float* be0;
  const float* g1; const float* be1;
  const float* addin;
  float* out;
};
struct LnBoth { LnArgs p[2]; };

__global__ __launch_bounds__(256) void ln_k(LnBoth args) {
  const LnArgs a = args.p[blockIdx.z];
  const int wid = threadIdx.x >> 6, lane = threadIdx.x & 63;
  const int row = blockIdx.x * 4 + wid;
  const size_t off = (size_t)row * 256 + lane * 4;

  const float4 x0 = *(const float4*)(a.x0 + off);
  const float4 x1 = *(const float4*)(a.x1 + off);
  float s0 = x0.x + x0.y + x0.z + x0.w;
  float s1 = x1.x + x1.y + x1.z + x1.w;
  #pragma unroll
  for (int s = 1; s < 64; s <<= 1) { s0 += __shfl_xor(s0, s, 64); s1 += __shfl_xor(s1, s, 64); }
  const float mu0 = s0 * (1.f / 256.f), mu1 = s1 * (1.f / 256.f);
  const float d0x = x0.x - mu0, d0y = x0.y - mu0, d0z = x0.z - mu0, d0w = x0.w - mu0;
  const float d1x = x1.x - mu1, d1y = x1.y - mu1, d1z = x1.z - mu1, d1w = x1.w - mu1;
  float v0 = d0x * d0x + d0y * d0y + d0z * d0z + d0w * d0w;
  float v1 = d1x * d1x + d1y * d1y + d1z * d1z + d1w * d1w;
  #pragma unroll
  for (int s = 1; s < 64; s <<= 1) { v0 += __shfl_xor(v0, s, 64); v1 += __shfl_xor(v1, s, 64); }
  const float r0 = rsqrtf(v0 * (1.f / 256.f) + 1e-5f);
  const float r1 = rsqrtf(v1 * (1.f / 256.f) + 1e-5f);

  const size_t po = (size_t)lane * 4;
  const float4 g0 = *(const float4*)(a.g0 + po), b0 = *(const float4*)(a.be0 + po);
  const float4 g1 = *(const float4*)(a.g1 + po), b1 = *(const float4*)(a.be1 + po);

  float4 y;
  y.x = fmaxf(d0x * r0 * g0.x + b0.x + d1x * r1 * g1.x + b1.x, 0.f);
  y.y = fmaxf(d0y * r0 * g0.y + b0.y + d1y * r1 * g1.y + b1.y, 0.f);
  y.z = fmaxf(d0z * r0 * g0.z + b0.z + d1z * r1 * g1.z + b1.z, 0.f);
  y.w = fmaxf(d0w * r0 * g0.w + b0.w + d1w * r1 * g1.w + b1.w, 0.f);
  if (a.addin) {
    const float4 ad = *(const float4*)(a.addin + off);
    y.x += ad.x; y.y += ad.y; y.z += ad.z; y.w += ad.w;
  }
  *(float4*)(a.out + off) = y;
}

// ---------------------------------------------------------------------------
// Host launch
// ---------------------------------------------------------------------------
extern "C" void kernel_launch(void* const* d_in, const int* in_sizes, int n_in,
                              void* d_out, int out_size, void* d_ws, size_t ws_size,
                              hipStream_t stream) {
  (void)in_sizes; (void)n_in; (void)out_size; (void)ws_size;
  const float* h_a = (const float*)d_in[0];
  const float* h_b = (const float*)d_in[1];
  const float* bq  = (const float*)d_in[7];
  const float* bk  = (const float*)d_in[9];
  const float* bv  = (const float*)d_in[11];
  const float* bo  = (const float*)d_in[13];
  const float* lng = (const float*)d_in[14];
  const float* lnb = (const float*)d_in[15];

  // log2(e)/sqrt(dk): folds softmax scale + exp->exp2 into Q projection
  const float QSC = 1.4426950408889634f * 0.17677669529663687f;

  char* ws = (char*)d_ws;
  uint16_t* WT   = (uint16_t*)ws;                        // 4 MB
  uint32_t* ADJB = (uint32_t*)(ws + (4u  << 20));        // 2 MB (transposed)
  float*    hA   = (float*)   (ws + (6u  << 20));        // 4 MB
  float*    hB   = (float*)   (ws + (10u << 20));        // 4 MB
  uint16_t* Qb[4]; uint16_t* Kb[4]; uint16_t* Vtb[4]; uint16_t* ATb[4]; float* MO[4];
  for (int j = 0; j < 4; ++j) {
    Qb[j]  = (uint16_t*)(ws + (14u << 20) + (size_t)j * (2u << 20));
    Kb[j]  = (uint16_t*)(ws + (22u << 20) + (size_t)j * (2u << 20));
    Vtb[j] = (uint16_t*)(ws + (30u << 20) + (size_t)j * (2u << 20));
    ATb[j] = (uint16_t*)(ws + (38u << 20) + (size_t)j * (2u << 20));
    MO[j]  = (float*)   (ws + (46u << 20) + (size_t)j * (4u << 20));
  }

  wprep_k<<<dim3(4, 4, 32), 256, 0, stream>>>(
      (const float*)d_in[6], (const float*)d_in[8],
      (const float*)d_in[10], (const float*)d_in[12], WT);
  {
    AdjArgs aa;
    for (int j = 0; j < 4; ++j) {
      aa.adj[j]  = (const int*)d_in[2 + j];
      aa.bits[j] = ADJB + (size_t)j * 131072;
    }
    adjbits_k<<<dim3(16384, 1, 4), 256, 0, stream>>>(aa);
  }

  for (int i = 0; i < 2; ++i) {
    const float* inA = (i == 0) ? h_a : hA;
    const float* inB = (i == 0) ? h_b : hB;
    const float* qin[4]  = { inA, inB, inB, inA };   // a2a, b2b, a2b, b2a
    const float* kvin[4] = { inA, inB, inA, inB };

    {
      GemmArgs ga;
      for (int j = 0; j < 4; ++j) {
        const int mm = i * 4 + j;
        ga.A[j]     = qin[j];  ga.W[j]     = WT + 0 * 524288 + (size_t)mm * 65536;
        ga.bias[j]  = bq + mm * 256; ga.res[j] = nullptr; ga.C[j] = Qb[j];
        ga.os[j]    = QSC;
        ga.A[4+j]   = kvin[j]; ga.W[4+j]   = WT + 1 * 524288 + (size_t)mm * 65536;
        ga.bias[4+j]= bk + mm * 256; ga.res[4+j] = nullptr; ga.C[4+j] = Kb[j];
        ga.os[4+j]  = 1.0f;
        ga.A[8+j]   = kvin[j]; ga.W[8+j]   = WT + 2 * 524288 + (size_t)mm * 65536;
        ga.bias[8+j]= bv + mm * 256; ga.res[8+j] = nullptr; ga.C[8+j] = ATb[j];
        ga.os[8+j]  = 1.0f;
      }
      gemm_k<0, 0><<<dim3(2, 32, 12), 256, 0, stream>>>(ga);
    }
    {
      VtArgs va;
      for (int j = 0; j < 4; ++j) { va.v[j] = ATb[j]; va.vt[j] = Vtb[j]; }
      vtrans_k<<<dim3(16, 32, 4), 256, 0, stream>>>(va);
    }
    {
      AttnArgs at;
      for (int j = 0; j < 4; ++j) {
        at.Q[j] = Qb[j]; at.K[j] = Kb[j]; at.Vt[j] = Vtb[j];
        at.adjb[j] = ADJB + (size_t)j * 131072; at.O[j] = ATb[j];
      }
      attn_k<<<dim3(1024, 1, 1), 256, 0, stream>>>(at);
    }
    {
      GemmArgs go = {};
      for (int j = 0; j < 4; ++j) {
        const int mm = i * 4 + j;
        go.A[j] = ATb[j]; go.W[j] = WT + 3 * 524288 + (size_t)mm * 65536;
        go.bias[j] = bo + mm * 256; go.res[j] = qin[j]; go.C[j] = MO[j];
        go.os[j] = 1.0f;
      }
      gemm_k<1, 1><<<dim3(2, 32, 4), 256, 0, stream>>>(go);
    }
    {
      LnBoth lb;
      float* outA = (i == 1) ? (float*)d_out : hA;
      float* outB = (i == 1) ? ((float*)d_out + 1048576) : hB;
      const float* addA = (i == 1) ? h_a : nullptr;
      const float* addB = (i == 1) ? h_b : nullptr;
      lb.p[0] = { MO[0], MO[3],
                  lng + (i * 4 + 0) * 256, lnb + (i * 4 + 0) * 256,
                  lng + (i * 4 + 3) * 256, lnb + (i * 4 + 3) * 256,
                  addA, outA };
      lb.p[1] = { MO[1], MO[2],
                  lng + (i * 4 + 1) * 256, lnb + (i * 4 + 1) * 256,
                  lng + (i * 4 + 2) * 256, lnb + (i * 4 + 2) * 256,
                  addB, outB };
      ln_k<<<dim3(1024, 1, 2), 256, 0, stream>>>(lb);
    }
  }
}

// Round 5
// 281.144 us; speedup vs baseline: 1.4078x; 1.0473x over previous
//
#include <hip/hip_runtime.h>
#include <hip/hip_bf16.h>
#include <stdint.h>

// ---------------------------------------------------------------------------
// Co-Guiding GAT forward: 2 layers x 4 masked-MHA branches, B=4 N=1024 D=256
// H=8 dk=32.
// R5: attn pack via __float22bfloat162_rn (hw cvt_pk, compiler-generated);
// phi-permuted Vt removes the cross-half exchange; GEMM gets global_load_lds
// + double-buffered 2-phase + XOR-swizzled ds_reads; all GEMM A-inputs bf16.
// ---------------------------------------------------------------------------

using bf16x8 = __attribute__((ext_vector_type(8))) short;   // 8 bf16 (4 VGPRs)
using f32x4  = __attribute__((ext_vector_type(4))) float;
using f32x16 = __attribute__((ext_vector_type(16))) float;

#define DEVI __device__ __forceinline__

DEVI uint16_t f2bf(float x) {                 // RNE f32 -> bf16 bits
  uint32_t u = __float_as_uint(x);
  u += 0x7FFFu + ((u >> 16) & 1u);
  return (uint16_t)(u >> 16);
}
DEVI uint32_t packbf2(float lo, float hi) {   // hw v_cvt_pk_bf16_f32 via API
  union { __hip_bfloat162 h; uint32_t u; } cv;
  cv.h = __float22bfloat162_rn(make_float2(lo, hi));
  return cv.u;
}

// ---------------------------------------------------------------------------
// Weight prep: W[k][n] fp32 -> Wt[n][k] bf16, for 4 types x 8 mats (L*4).
// ---------------------------------------------------------------------------
__global__ __launch_bounds__(256) void wprep_k(const float* __restrict__ Wq,
                                               const float* __restrict__ Wk,
                                               const float* __restrict__ Wv,
                                               const float* __restrict__ Wo,
                                               uint16_t* __restrict__ out) {
  const int z = blockIdx.z;
  const int type = z >> 3, mat = z & 7;
  const float* W = (type == 0 ? Wq : type == 1 ? Wk : type == 2 ? Wv : Wo)
                   + (size_t)mat * 65536;
  uint16_t* o = out + (size_t)type * 524288 + (size_t)mat * 65536;
  const int r0 = blockIdx.y * 64, c0 = blockIdx.x * 64;
  __shared__ float tl[64][68];
  const int t = threadIdx.x;
  {
    const int rr = t >> 2, cb = (t & 3) * 16;
    const float* src = W + (size_t)(r0 + rr) * 256 + c0 + cb;
    #pragma unroll
    for (int q = 0; q < 4; ++q) {
      float4 v = *(const float4*)(src + q * 4);
      tl[rr][cb + q*4 + 0] = v.x; tl[rr][cb + q*4 + 1] = v.y;
      tl[rr][cb + q*4 + 2] = v.z; tl[rr][cb + q*4 + 3] = v.w;
    }
  }
  __syncthreads();
  {
    const int nn = t >> 2, kb = (t & 3) * 16;
    __align__(16) uint16_t tmp[16];
    #pragma unroll
    for (int q = 0; q < 16; ++q) tmp[q] = f2bf(tl[kb + q][nn]);
    uint16_t* dst = o + (size_t)(c0 + nn) * 256 + r0 + kb;
    *(uint4*)&dst[0] = *(uint4*)&tmp[0];
    *(uint4*)&dst[8] = *(uint4*)&tmp[8];
  }
}

// ---------------------------------------------------------------------------
// fp32 -> bf16 copies of layer-0 inputs
// ---------------------------------------------------------------------------
__global__ __launch_bounds__(256) void cvt_k(const float* __restrict__ a,
                                             const float* __restrict__ b,
                                             uint16_t* __restrict__ oa,
                                             uint16_t* __restrict__ ob) {
  const size_t i = ((size_t)blockIdx.x * 256 + threadIdx.x) * 8;
  const float* s = blockIdx.y ? b : a;
  uint16_t* o = blockIdx.y ? ob : oa;
  const float4 f0 = *(const float4*)(s + i), f1 = *(const float4*)(s + i + 4);
  uint4 u;
  u.x = packbf2(f0.x, f0.y); u.y = packbf2(f0.z, f0.w);
  u.z = packbf2(f1.x, f1.y); u.w = packbf2(f1.z, f1.w);
  *(uint4*)(o + i) = u;
}

// ---------------------------------------------------------------------------
// Adjacency -> TRANSPOSED bitmask: adj[b][q][k] -> bits[b][kw][q] (kw = k/32)
// ---------------------------------------------------------------------------
struct AdjArgs { const int* adj[4]; uint32_t* bits[4]; };

__global__ __launch_bounds__(256) void adjbits_k(AdjArgs a) {
  const int* adj = a.adj[blockIdx.z];
  uint32_t* bits = a.bits[blockIdx.z];
  const size_t i = (size_t)blockIdx.x * 256 + threadIdx.x;
  const int lane = threadIdx.x & 63;
  const int v = adj[i];
  unsigned long long m = __ballot(v != 0);
  if ((lane & 31) == 0) {
    const uint32_t wi = (uint32_t)(i >> 5);      // (b*1024+q)*32 + kw
    const uint32_t kw = wi & 31;
    const uint32_t q  = (wi >> 5) & 1023;
    const uint32_t bb = wi >> 15;
    bits[((bb * 32 + kw) << 10) | q] = (uint32_t)(m >> (lane & 32));
  }
}

// ---------------------------------------------------------------------------
// GEMM: C[4096][256] = (Abf[4096][256] @ W[256][256] + bias) * os (+res).
// A always bf16.  global_load_lds staging, double-buffered LDS, one barrier
// per 32-K step (T3 2-phase).  ds_read XOR swizzle (2-way max): linear LDS
// dest (gload_lds requirement) + pre-swizzled global SOURCE + swizzled read.
// ---------------------------------------------------------------------------
struct GemmArgs {
  const uint16_t* A[12];
  const uint16_t* W[12];
  const float*    bias[12];
  const float*    res[12];
  void*           C[12];
  float           os[12];
};

DEVI void stage_tile(const uint16_t* __restrict__ Ab,
                     const uint16_t* __restrict__ Wt,
                     int m0, int n0, int kk,
                     char* AsB, char* BsB, int wid, int lane) {
  #pragma unroll
  for (int i = 0; i < 2; ++i) {
    const int seg = i * 4 + wid;                    // 16-row segment 0..7
    const int rl  = (seg << 4) + (lane >> 2);       // linear LDS row
    const int gs  = (lane & 3) ^ ((lane >> 3) & 3); // pre-swizzled src chunk
    const uint16_t* gA = Ab + (size_t)(m0 + rl) * 256 + kk + gs * 8;
    const uint16_t* gB = Wt + (size_t)(n0 + rl) * 256 + kk + gs * 8;
    __builtin_amdgcn_global_load_lds(
        (const __attribute__((address_space(1))) void*)gA,
        (__attribute__((address_space(3))) void*)(AsB + (seg << 10)), 16, 0, 0);
    __builtin_amdgcn_global_load_lds(
        (const __attribute__((address_space(1))) void*)gB,
        (__attribute__((address_space(3))) void*)(BsB + (seg << 10)), 16, 0, 0);
  }
}

template <int RESOUT>
__global__ __launch_bounds__(256) void gemm_k(GemmArgs args) {
  const int z  = blockIdx.z;
  const int m0 = blockIdx.y * 128, n0 = blockIdx.x * 128;
  const uint16_t* Ab = args.A[z];
  const uint16_t* Wt = args.W[z];
  __shared__ __align__(16) uint16_t As[2][4096];   // [128][32] per buffer
  __shared__ __align__(16) uint16_t Bs[2][4096];
  const int t = threadIdx.x;
  const int lane = t & 63, wid = t >> 6;
  const int g = lane >> 4, c = lane & 15;
  const int gx = g ^ ((c >> 1) & 3);               // swizzled read chunk
  const int wm = (wid >> 1) * 64, wn = (wid & 1) * 64;
  f32x4 acc[4][4] = {};

  stage_tile(Ab, Wt, m0, n0, 0, (char*)As[0], (char*)Bs[0], wid, lane);
  __syncthreads();

  for (int ks = 0; ks < 8; ++ks) {
    const int buf = ks & 1;
    if (ks < 7)
      stage_tile(Ab, Wt, m0, n0, (ks + 1) * 32,
                 (char*)As[buf ^ 1], (char*)Bs[buf ^ 1], wid, lane);
    bf16x8 af[4], bfr[4];
    #pragma unroll
    for (int mt = 0; mt < 4; ++mt)
      af[mt]  = *(const bf16x8*)&As[buf][(wm + mt * 16 + c) * 32 + gx * 8];
    #pragma unroll
    for (int nt = 0; nt < 4; ++nt)
      bfr[nt] = *(const bf16x8*)&Bs[buf][(wn + nt * 16 + c) * 32 + gx * 8];
    #pragma unroll
    for (int mt = 0; mt < 4; ++mt)
      #pragma unroll
      for (int nt = 0; nt < 4; ++nt)
        acc[mt][nt] = __builtin_amdgcn_mfma_f32_16x16x32_bf16(af[mt], bfr[nt], acc[mt][nt], 0, 0, 0);
    if (ks < 7) __syncthreads();
  }

  const float* bias = args.bias[z];
  const float osz = args.os[z];
  float bv[4];
  #pragma unroll
  for (int nt = 0; nt < 4; ++nt) bv[nt] = bias[n0 + wn + nt * 16 + c];

  if (RESOUT) {
    const float* res = args.res[z];
    float* C = (float*)args.C[z];
    #pragma unroll
    for (int mt = 0; mt < 4; ++mt)
      #pragma unroll
      for (int r = 0; r < 4; ++r) {
        const int row = m0 + wm + mt * 16 + 4 * g + r;
        #pragma unroll
        for (int nt = 0; nt < 4; ++nt) {
          const int col = n0 + wn + nt * 16 + c;
          C[(size_t)row * 256 + col] = (acc[mt][nt][r] + bv[nt]) * osz + res[(size_t)row * 256 + col];
        }
      }
  } else {
    uint16_t* C = (uint16_t*)args.C[z];
    #pragma unroll
    for (int mt = 0; mt < 4; ++mt)
      #pragma unroll
      for (int r = 0; r < 4; ++r) {
        const int row = m0 + wm + mt * 16 + 4 * g + r;
        #pragma unroll
        for (int nt = 0; nt < 4; ++nt) {
          const int col = n0 + wn + nt * 16 + c;
          C[(size_t)row * 256 + col] = f2bf((acc[mt][nt][r] + bv[nt]) * osz);
        }
      }
  }
}

// ---------------------------------------------------------------------------
// V transpose with phi permutation: Vt[d][blk*16 + m] = V[blk*16 + phi(m)][d]
// phi swaps the middle quads of each 16-block (involution) so the attention
// PV B-fragment is lane-local (no cross-half exchange needed).
// ---------------------------------------------------------------------------
struct VtArgs { const uint16_t* v[4]; uint16_t* vt[4]; };

__global__ __launch_bounds__(256) void vtrans_k(VtArgs args) {
  const int j = blockIdx.z;
  const int bh = blockIdx.y, b = bh >> 3, h = bh & 7;
  const int n0 = blockIdx.x * 64;
  __shared__ __align__(16) uint16_t tl[64][32];
  const int t = threadIdx.x;
  {
    const int n = t >> 2, d0 = (t & 3) * 8;
    *(uint4*)&tl[n][d0] =
      *(const uint4*)&args.v[j][(size_t)(b * 1024 + n0 + n) * 256 + h * 32 + d0];
  }
  __syncthreads();
  {
    const int d = t & 31, blk = (t >> 5) & 3, sub = t >> 7;
    __align__(16) uint16_t tmp[8];
    #pragma unroll
    for (int q = 0; q < 8; ++q) {
      const int m = sub * 8 + q;
      const int phi = ((m & 4) << 1) | ((m & 8) >> 1) | (m & 3);
      tmp[q] = tl[blk * 16 + phi][d];
    }
    uint16_t* dst = args.vt[j] + ((size_t)(b * 8 + h) * 32 + d) * 1024
                    + n0 + blk * 16 + sub * 8;
    *(uint4*)dst = *(uint4*)tmp;
  }
}

// ---------------------------------------------------------------------------
// Fused masked flash attention, 32x32 MFMA, zero LDS, no cross-lane P moves.
// Lane (c=lane&31, hi=lane>>5) owns q-row c's state; st[r] = S[q=c][kk] with
// kk=(r&3)+8*(r>>2)+4*hi.  P packs [u0..u3]/[u4..u7] feed PV directly since
// Vt is phi-permuted.  Mask-before-max, fresh online rescale (R4 numerics).
// ---------------------------------------------------------------------------
struct AttnArgs {
  const uint16_t* Q[4];
  const uint16_t* K[4];
  const uint16_t* Vt[4];
  const uint32_t* adjb[4];   // transposed [b][kw][q]
  uint16_t*       O[4];
};

__global__ __launch_bounds__(256) void attn_k(AttnArgs args) {
  const int bid = blockIdx.x;
  const int qt  = bid >> 7;           // 8 q-tiles per group
  const int grp = bid & 127;          // (branch,b,h) group -> same XCD
  const int bh = grp & 31, j = grp >> 5;
  const int b = bh >> 3, h = bh & 7;
  const int t = threadIdx.x, wid = t >> 6, lane = t & 63;
  const int c = lane & 31, hi = lane >> 5;
  const int qrow = qt * 128 + wid * 32 + c;

  const uint16_t* Q  = args.Q[j];
  const uint16_t* Kp = args.K[j] + (size_t)(b * 1024) * 256 + h * 32 + hi * 8;
  const uint16_t* Vp = args.Vt[j] + ((size_t)(b * 8 + h) * 32 + c) * 1024 + hi * 8;
  const uint32_t* adjT = args.adjb[j] + (size_t)b * 32768 + qrow;

  const size_t qoff = (size_t)(b * 1024 + qrow) * 256 + h * 32 + hi * 8;
  const bf16x8 qf0 = *(const bf16x8*)&Q[qoff];
  const bf16x8 qf1 = *(const bf16x8*)&Q[qoff + 16];

  f32x16 oacc = {};
  float m = -3.0e38f, l = 0.f;

  for (int k0 = 0; k0 < 1024; k0 += 32) {
    const uint32_t w = adjT[(size_t)(k0 >> 5) << 10] >> (hi * 4);
    const uint16_t* kr = Kp + (size_t)(k0 + c) * 256;
    const bf16x8 kf0 = *(const bf16x8*)kr;
    const bf16x8 kf1 = *(const bf16x8*)(kr + 16);
    const bf16x8 vf0 = *(const bf16x8*)(Vp + k0);        // issued early;
    const bf16x8 vf1 = *(const bf16x8*)(Vp + k0 + 16);   // used post-softmax

    f32x16 st = {};
    st = __builtin_amdgcn_mfma_f32_32x32x16_bf16(kf0, qf0, st, 0, 0, 0);
    st = __builtin_amdgcn_mfma_f32_32x32x16_bf16(kf1, qf1, st, 0, 0, 0);

    // mask BEFORE max (reference semantics): masked -> -1e9
    #pragma unroll
    for (int r = 0; r < 16; ++r) {
      const int pos = (r & 3) + 8 * (r >> 2);   // bit pos (w pre-shifted by 4*hi)
      st[r] = ((w >> pos) & 1u) ? st[r] : -1.0e9f;
    }

    float a0 = fmaxf(fmaxf(st[0],  st[1]),  fmaxf(st[2],  st[3]));
    float a1 = fmaxf(fmaxf(st[4],  st[5]),  fmaxf(st[6],  st[7]));
    float a2 = fmaxf(fmaxf(st[8],  st[9]),  fmaxf(st[10], st[11]));
    float a3 = fmaxf(fmaxf(st[12], st[13]), fmaxf(st[14], st[15]));
    float tm = fmaxf(fmaxf(a0, a1), fmaxf(a2, a3));
    tm = fmaxf(tm, __shfl_xor(tm, 32, 64));     // cross-half pair max

    const float mn = fmaxf(m, tm);
    const float al = __builtin_exp2f(m - mn);
    m = mn; l *= al;
    #pragma unroll
    for (int r = 0; r < 16; ++r) oacc[r] *= al;

    float s0 = 0.f, s1 = 0.f, s2 = 0.f, s3 = 0.f;
    #pragma unroll
    for (int r = 0; r < 16; ++r) {
      const float pv = __builtin_exp2f(st[r] - m);   // masked: exp2(-1e9-m)=0
      st[r] = pv;
      if ((r & 3) == 0) s0 += pv; else if ((r & 3) == 1) s1 += pv;
      else if ((r & 3) == 2) s2 += pv; else s3 += pv;
    }
    l += (s0 + s1) + (s2 + s3);

    union PU { uint32_t u[4]; bf16x8 v; };
    PU p0, p1;
    p0.u[0] = packbf2(st[0],  st[1]);  p0.u[1] = packbf2(st[2],  st[3]);
    p0.u[2] = packbf2(st[4],  st[5]);  p0.u[3] = packbf2(st[6],  st[7]);
    p1.u[0] = packbf2(st[8],  st[9]);  p1.u[1] = packbf2(st[10], st[11]);
    p1.u[2] = packbf2(st[12], st[13]); p1.u[3] = packbf2(st[14], st[15]);

    oacc = __builtin_amdgcn_mfma_f32_32x32x16_bf16(vf0, p0.v, oacc, 0, 0, 0);
    oacc = __builtin_amdgcn_mfma_f32_32x32x16_bf16(vf1, p1.v, oacc, 0, 0, 0);
  }

  l += __shfl_xor(l, 32, 64);
  const float inv = 1.0f / l;
  uint16_t* O = args.O[j];
  const size_t ob = (size_t)(b * 1024 + qrow) * 256 + h * 32 + 4 * hi;
  #pragma unroll
  for (int rq = 0; rq < 4; ++rq) {
    uint2 val;
    val.x = packbf2(oacc[4*rq+0] * inv, oacc[4*rq+1] * inv);
    val.y = packbf2(oacc[4*rq+2] * inv, oacc[4*rq+3] * inv);
    *(uint2*)&O[ob + 8 * rq] = val;
  }
}

// ---------------------------------------------------------------------------
// Fused LayerNorm(x0)+LayerNorm(x1) -> relu(sum) (+ optional input residual)
// Optionally writes a bf16 mirror (next layer's GEMM A input).
// ---------------------------------------------------------------------------
struct LnArgs {
  const float* x0; const float* x1;
  const float* g0; const float* be0;
  const float* g1; const float* be1;
  const float* addin;
  float* out;
  uint16_t* outbf;
};
struct LnBoth { LnArgs p[2]; };

__global__ __launch_bounds__(256) void ln_k(LnBoth args) {
  const LnArgs a = args.p[blockIdx.z];
  const int wid = threadIdx.x >> 6, lane = threadIdx.x & 63;
  const int row = blockIdx.x * 4 + wid;
  const size_t off = (size_t)row * 256 + lane * 4;

  const float4 x0 = *(const float4*)(a.x0 + off);
  const float4 x1 = *(const float4*)(a.x1 + off);
  float s0 = x0.x + x0.y + x0.z + x0.w;
  float s1 = x1.x + x1.y + x1.z + x1.w;
  #pragma unroll
  for (int s = 1; s < 64; s <<= 1) { s0 += __shfl_xor(s0, s, 64); s1 += __shfl_xor(s1, s, 64); }
  const float mu0 = s0 * (1.f / 256.f), mu1 = s1 * (1.f / 256.f);
  const float d0x = x0.x - mu0, d0y = x0.y - mu0, d0z = x0.z - mu0, d0w = x0.w - mu0;
  const float d1x = x1.x - mu1, d1y = x1.y - mu1, d1z = x1.z - mu1, d1w = x1.w - mu1;
  float v0 = d0x * d0x + d0y * d0y + d0z * d0z + d0w * d0w;
  float v1 = d1x * d1x + d1y * d1y + d1z * d1z + d1w * d1w;
  #pragma unroll
  for (int s = 1; s < 64; s <<= 1) { v0 += __shfl_xor(v0, s, 64); v1 += __shfl_xor(v1, s, 64); }
  const float r0 = rsqrtf(v0 * (1.f / 256.f) + 1e-5f);
  const float r1 = rsqrtf(v1 * (1.f / 256.f) + 1e-5f);

  const size_t po = (size_t)lane * 4;
  const float4 g0 = *(const float4*)(a.g0 + po), b0 = *(const float4*)(a.be0 + po);
  const float4 g1 = *(const float4*)(a.g1 + po), b1 = *(const float4*)(a.be1 + po);

  float4 y;
  y.x = fmaxf(d0x * r0 * g0.x + b0.x + d1x * r1 * g1.x + b1.x, 0.f);
  y.y = fmaxf(d0y * r0 * g0.y + b0.y + d1y * r1 * g1.y + b1.y, 0.f);
  y.z = fmaxf(d0z * r0 * g0.z + b0.z + d1z * r1 * g1.z + b1.z, 0.f);
  y.w = fmaxf(d0w * r0 * g0.w + b0.w + d1w * r1 * g1.w + b1.w, 0.f);
  if (a.addin) {
    const float4 ad = *(const float4*)(a.addin + off);
    y.x += ad.x; y.y += ad.y; y.z += ad.z; y.w += ad.w;
  }
  *(float4*)(a.out + off) = y;
  if (a.outbf) {
    uint2 vb;
    vb.x = packbf2(y.x, y.y); vb.y = packbf2(y.z, y.w);
    *(uint2*)(a.outbf + off) = vb;
  }
}

// ---------------------------------------------------------------------------
// Host launch
// ---------------------------------------------------------------------------
extern "C" void kernel_launch(void* const* d_in, const int* in_sizes, int n_in,
                              void* d_out, int out_size, void* d_ws, size_t ws_size,
                              hipStream_t stream) {
  (void)in_sizes; (void)n_in; (void)out_size; (void)ws_size;
  const float* h_a = (const float*)d_in[0];
  const float* h_b = (const float*)d_in[1];
  const float* bq  = (const float*)d_in[7];
  const float* bk  = (const float*)d_in[9];
  const float* bv  = (const float*)d_in[11];
  const float* bo  = (const float*)d_in[13];
  const float* lng = (const float*)d_in[14];
  const float* lnb = (const float*)d_in[15];

  // log2(e)/sqrt(dk): folds softmax scale + exp->exp2 into Q projection
  const float QSC = 1.4426950408889634f * 0.17677669529663687f;

  char* ws = (char*)d_ws;
  uint16_t* WT   = (uint16_t*)ws;                        // 0-4 MB
  uint32_t* ADJB = (uint32_t*)(ws + (4u  << 20));        // 4-6 MB (transposed)
  float*    hA   = (float*)   (ws + (6u  << 20));        // 6-10 MB
  float*    hB   = (float*)   (ws + (10u << 20));        // 10-14 MB
  uint16_t* hAbf = (uint16_t*)(ws + (14u << 20));        // 14-16 MB
  uint16_t* hBbf = (uint16_t*)(ws + (16u << 20));        // 16-18 MB
  uint16_t* Qb[4]; uint16_t* Kb[4]; uint16_t* Vtb[4]; uint16_t* ATb[4]; float* MO[4];
  for (int j = 0; j < 4; ++j) {
    Qb[j]  = (uint16_t*)(ws + (18u << 20) + (size_t)j * (2u << 20));  // 18-26
    Kb[j]  = (uint16_t*)(ws + (26u << 20) + (size_t)j * (2u << 20));  // 26-34
    MO[j]  = (float*)   (ws + (18u << 20) + (size_t)j * (4u << 20));  // 18-34 (over Qb/Kb, dead by then)
    Vtb[j] = (uint16_t*)(ws + (34u << 20) + (size_t)j * (2u << 20));  // 34-42
    ATb[j] = (uint16_t*)(ws + (42u << 20) + (size_t)j * (2u << 20));  // 42-50
  }

  wprep_k<<<dim3(4, 4, 32), 256, 0, stream>>>(
      (const float*)d_in[6], (const float*)d_in[8],
      (const float*)d_in[10], (const float*)d_in[12], WT);
  cvt_k<<<dim3(512, 2), 256, 0, stream>>>(h_a, h_b, hAbf, hBbf);
  {
    AdjArgs aa;
    for (int j = 0; j < 4; ++j) {
      aa.adj[j]  = (const int*)d_in[2 + j];
      aa.bits[j] = ADJB + (size_t)j * 131072;
    }
    adjbits_k<<<dim3(16384, 1, 4), 256, 0, stream>>>(aa);
  }

  for (int i = 0; i < 2; ++i) {
    const float* inA = (i == 0) ? h_a : hA;       // fp32 (residual for O-proj)
    const float* inB = (i == 0) ? h_b : hB;
    const float* qin[4]   = { inA, inB, inB, inA };   // a2a, b2b, a2b, b2a
    const uint16_t* qbf[4]  = { hAbf, hBbf, hBbf, hAbf };
    const uint16_t* kvbf[4] = { hAbf, hBbf, hAbf, hBbf };

    {
      GemmArgs ga = {};
      for (int j = 0; j < 4; ++j) {
        const int mm = i * 4 + j;
        ga.A[j]     = qbf[j];  ga.W[j]     = WT + 0 * 524288 + (size_t)mm * 65536;
        ga.bias[j]  = bq + mm * 256; ga.C[j] = Qb[j];  ga.os[j] = QSC;
        ga.A[4+j]   = kvbf[j]; ga.W[4+j]   = WT + 1 * 524288 + (size_t)mm * 65536;
        ga.bias[4+j]= bk + mm * 256; ga.C[4+j] = Kb[j]; ga.os[4+j] = 1.0f;
        ga.A[8+j]   = kvbf[j]; ga.W[8+j]   = WT + 2 * 524288 + (size_t)mm * 65536;
        ga.bias[8+j]= bv + mm * 256; ga.C[8+j] = ATb[j]; ga.os[8+j] = 1.0f;
      }
      gemm_k<0><<<dim3(2, 32, 12), 256, 0, stream>>>(ga);
    }
    {
      VtArgs va;
      for (int j = 0; j < 4; ++j) { va.v[j] = ATb[j]; va.vt[j] = Vtb[j]; }
      vtrans_k<<<dim3(16, 32, 4), 256, 0, stream>>>(va);
    }
    {
      AttnArgs at;
      for (int j = 0; j < 4; ++j) {
        at.Q[j] = Qb[j]; at.K[j] = Kb[j]; at.Vt[j] = Vtb[j];
        at.adjb[j] = ADJB + (size_t)j * 131072; at.O[j] = ATb[j];
      }
      attn_k<<<dim3(1024, 1, 1), 256, 0, stream>>>(at);
    }
    {
      GemmArgs go = {};
      for (int j = 0; j < 4; ++j) {
        const int mm = i * 4 + j;
        go.A[j] = ATb[j]; go.W[j] = WT + 3 * 524288 + (size_t)mm * 65536;
        go.bias[j] = bo + mm * 256; go.res[j] = qin[j]; go.C[j] = MO[j];
        go.os[j] = 1.0f;
      }
      gemm_k<1><<<dim3(2, 32, 4), 256, 0, stream>>>(go);
    }
    {
      LnBoth lb;
      float* outA = (i == 1) ? (float*)d_out : hA;
      float* outB = (i == 1) ? ((float*)d_out + 1048576) : hB;
      const float* addA = (i == 1) ? h_a : nullptr;
      const float* addB = (i == 1) ? h_b : nullptr;
      uint16_t* mbA = (i == 0) ? hAbf : nullptr;   // bf16 mirror for next layer
      uint16_t* mbB = (i == 0) ? hBbf : nullptr;
      lb.p[0] = { MO[0], MO[3],
                  lng + (i * 4 + 0) * 256, lnb + (i * 4 + 0) * 256,
                  lng + (i * 4 + 3) * 256, lnb + (i * 4 + 3) * 256,
                  addA, outA, mbA };
      lb.p[1] = { MO[1], MO[2],
                  lng + (i * 4 + 1) * 256, lnb + (i * 4 + 1) * 256,
                  lng + (i * 4 + 2) * 256, lnb + (i * 4 + 2) * 256,
                  addB, outB, mbB };
      ln_k<<<dim3(1024, 1, 2), 256, 0, stream>>>(lb);
    }
  }
}

// Round 6
// 228.924 us; speedup vs baseline: 1.7290x; 1.2281x over previous
//
#include <hip/hip_runtime.h>
#include <hip/hip_bf16.h>
#include <stdint.h>

// ---------------------------------------------------------------------------
// Co-Guiding GAT forward: 2 layers x 4 masked-MHA branches, B=4 N=1024 D=256
// H=8 dk=32.
// R6: attn exp via __builtin_amdgcn_exp2f (bare v_exp_f32); fixed-shift
// softmax (m=12 in MFMA C-init, l-overflow guard) removes max/rescale VALU;
// Q/K in [b][h][n][32] layout (GEMM epilogue mode), V written phi-permuted
// by GEMM (vtrans deleted).  Masking: pv *= bit (superset-softmax identity).
// ---------------------------------------------------------------------------

using bf16x8 = __attribute__((ext_vector_type(8))) short;   // 8 bf16 (4 VGPRs)
using f32x4  = __attribute__((ext_vector_type(4))) float;
using f32x16 = __attribute__((ext_vector_type(16))) float;

#define DEVI __device__ __forceinline__

DEVI uint16_t f2bf(float x) {                 // RNE f32 -> bf16 bits
  uint32_t u = __float_as_uint(x);
  u += 0x7FFFu + ((u >> 16) & 1u);
  return (uint16_t)(u >> 16);
}
DEVI uint32_t packbf2(float lo, float hi) {   // hw v_cvt_pk_bf16_f32 via API
  union { __hip_bfloat162 h; uint32_t u; } cv;
  cv.h = __float22bfloat162_rn(make_float2(lo, hi));
  return cv.u;
}
DEVI int phi4(int m) {                        // swap bits 2<->3 (involution)
  return ((m & 4) << 1) | ((m & 8) >> 1) | (m & 3);
}

// ---------------------------------------------------------------------------
// Weight prep: W[k][n] fp32 -> Wt[n][k] bf16, for 4 types x 8 mats (L*4).
// ---------------------------------------------------------------------------
__global__ __launch_bounds__(256) void wprep_k(const float* __restrict__ Wq,
                                               const float* __restrict__ Wk,
                                               const float* __restrict__ Wv,
                                               const float* __restrict__ Wo,
                                               uint16_t* __restrict__ out) {
  const int z = blockIdx.z;
  const int type = z >> 3, mat = z & 7;
  const float* W = (type == 0 ? Wq : type == 1 ? Wk : type == 2 ? Wv : Wo)
                   + (size_t)mat * 65536;
  uint16_t* o = out + (size_t)type * 524288 + (size_t)mat * 65536;
  const int r0 = blockIdx.y * 64, c0 = blockIdx.x * 64;
  __shared__ float tl[64][68];
  const int t = threadIdx.x;
  {
    const int rr = t >> 2, cb = (t & 3) * 16;
    const float* src = W + (size_t)(r0 + rr) * 256 + c0 + cb;
    #pragma unroll
    for (int q = 0; q < 4; ++q) {
      float4 v = *(const float4*)(src + q * 4);
      tl[rr][cb + q*4 + 0] = v.x; tl[rr][cb + q*4 + 1] = v.y;
      tl[rr][cb + q*4 + 2] = v.z; tl[rr][cb + q*4 + 3] = v.w;
    }
  }
  __syncthreads();
  {
    const int nn = t >> 2, kb = (t & 3) * 16;
    __align__(16) uint16_t tmp[16];
    #pragma unroll
    for (int q = 0; q < 16; ++q) tmp[q] = f2bf(tl[kb + q][nn]);
    uint16_t* dst = o + (size_t)(c0 + nn) * 256 + r0 + kb;
    *(uint4*)&dst[0] = *(uint4*)&tmp[0];
    *(uint4*)&dst[8] = *(uint4*)&tmp[8];
  }
}

// ---------------------------------------------------------------------------
// fp32 -> bf16 copies of layer-0 inputs
// ---------------------------------------------------------------------------
__global__ __launch_bounds__(256) void cvt_k(const float* __restrict__ a,
                                             const float* __restrict__ b,
                                             uint16_t* __restrict__ oa,
                                             uint16_t* __restrict__ ob) {
  const size_t i = ((size_t)blockIdx.x * 256 + threadIdx.x) * 8;
  const float* s = blockIdx.y ? b : a;
  uint16_t* o = blockIdx.y ? ob : oa;
  const float4 f0 = *(const float4*)(s + i), f1 = *(const float4*)(s + i + 4);
  uint4 u;
  u.x = packbf2(f0.x, f0.y); u.y = packbf2(f0.z, f0.w);
  u.z = packbf2(f1.x, f1.y); u.w = packbf2(f1.z, f1.w);
  *(uint4*)(o + i) = u;
}

// ---------------------------------------------------------------------------
// Adjacency -> TRANSPOSED bitmask: adj[b][q][k] -> bits[b][kw][q] (kw = k/32)
// ---------------------------------------------------------------------------
struct AdjArgs { const int* adj[4]; uint32_t* bits[4]; };

__global__ __launch_bounds__(256) void adjbits_k(AdjArgs a) {
  const int* adj = a.adj[blockIdx.z];
  uint32_t* bits = a.bits[blockIdx.z];
  const size_t i = (size_t)blockIdx.x * 256 + threadIdx.x;
  const int lane = threadIdx.x & 63;
  const int v = adj[i];
  unsigned long long m = __ballot(v != 0);
  if ((lane & 31) == 0) {
    const uint32_t wi = (uint32_t)(i >> 5);      // (b*1024+q)*32 + kw
    const uint32_t kw = wi & 31;
    const uint32_t q  = (wi >> 5) & 1023;
    const uint32_t bb = wi >> 15;
    bits[((bb * 32 + kw) << 10) | q] = (uint32_t)(m >> (lane & 32));
  }
}

// ---------------------------------------------------------------------------
// GEMM: C = (Abf[4096][256] @ W[256][256] + bias) * os, epilogue mode per z:
//   mode 1: fp32 linear [row][col] + residual add (O-proj)
//   mode 2: bf16 [b][h][n][32] head-major (Q, K)
//   mode 3: bf16 Vt[(b,h)*32+d][1024] with phi-permuted n (V)
// global_load_lds staging, double-buffered, one barrier per 32-K step,
// XOR-swizzled ds_read (source-pre-swizzled; linear LDS dest).
// ---------------------------------------------------------------------------
struct GemmArgs {
  const uint16_t* A[12];
  const uint16_t* W[12];
  const float*    bias[12];
  const float*    res[12];
  void*           C[12];
  float           os[12];
  int             mode[12];
};

DEVI void stage_tile(const uint16_t* __restrict__ Ab,
                     const uint16_t* __restrict__ Wt,
                     int m0, int n0, int kk,
                     char* AsB, char* BsB, int wid, int lane) {
  #pragma unroll
  for (int i = 0; i < 2; ++i) {
    const int seg = i * 4 + wid;                    // 16-row segment 0..7
    const int rl  = (seg << 4) + (lane >> 2);       // linear LDS row
    const int gs  = (lane & 3) ^ ((lane >> 3) & 3); // pre-swizzled src chunk
    const uint16_t* gA = Ab + (size_t)(m0 + rl) * 256 + kk + gs * 8;
    const uint16_t* gB = Wt + (size_t)(n0 + rl) * 256 + kk + gs * 8;
    __builtin_amdgcn_global_load_lds(
        (const __attribute__((address_space(1))) void*)gA,
        (__attribute__((address_space(3))) void*)(AsB + (seg << 10)), 16, 0, 0);
    __builtin_amdgcn_global_load_lds(
        (const __attribute__((address_space(1))) void*)gB,
        (__attribute__((address_space(3))) void*)(BsB + (seg << 10)), 16, 0, 0);
  }
}

__global__ __launch_bounds__(256) void gemm_k(GemmArgs args) {
  const int z  = blockIdx.z;
  const int m0 = blockIdx.y * 128, n0 = blockIdx.x * 128;
  const uint16_t* Ab = args.A[z];
  const uint16_t* Wt = args.W[z];
  __shared__ __align__(16) uint16_t As[2][4096];   // [128][32] per buffer
  __shared__ __align__(16) uint16_t Bs[2][4096];
  const int t = threadIdx.x;
  const int lane = t & 63, wid = t >> 6;
  const int g = lane >> 4, c = lane & 15;
  const int gx = g ^ ((c >> 1) & 3);               // swizzled read chunk
  const int wm = (wid >> 1) * 64, wn = (wid & 1) * 64;
  f32x4 acc[4][4] = {};

  stage_tile(Ab, Wt, m0, n0, 0, (char*)As[0], (char*)Bs[0], wid, lane);
  __syncthreads();

  for (int ks = 0; ks < 8; ++ks) {
    const int buf = ks & 1;
    if (ks < 7)
      stage_tile(Ab, Wt, m0, n0, (ks + 1) * 32,
                 (char*)As[buf ^ 1], (char*)Bs[buf ^ 1], wid, lane);
    bf16x8 af[4], bfr[4];
    #pragma unroll
    for (int mt = 0; mt < 4; ++mt)
      af[mt]  = *(const bf16x8*)&As[buf][(wm + mt * 16 + c) * 32 + gx * 8];
    #pragma unroll
    for (int nt = 0; nt < 4; ++nt)
      bfr[nt] = *(const bf16x8*)&Bs[buf][(wn + nt * 16 + c) * 32 + gx * 8];
    #pragma unroll
    for (int mt = 0; mt < 4; ++mt)
      #pragma unroll
      for (int nt = 0; nt < 4; ++nt)
        acc[mt][nt] = __builtin_amdgcn_mfma_f32_16x16x32_bf16(af[mt], bfr[nt], acc[mt][nt], 0, 0, 0);
    if (ks < 7) __syncthreads();
  }

  const float* bias = args.bias[z];
  const float osz = args.os[z];
  const int mode = args.mode[z];
  float bv[4];
  #pragma unroll
  for (int nt = 0; nt < 4; ++nt) bv[nt] = bias[n0 + wn + nt * 16 + c];

  if (mode == 1) {
    const float* res = args.res[z];
    float* C = (float*)args.C[z];
    #pragma unroll
    for (int mt = 0; mt < 4; ++mt)
      #pragma unroll
      for (int r = 0; r < 4; ++r) {
        const int row = m0 + wm + mt * 16 + 4 * g + r;
        #pragma unroll
        for (int nt = 0; nt < 4; ++nt) {
          const int col = n0 + wn + nt * 16 + c;
          C[(size_t)row * 256 + col] = (acc[mt][nt][r] + bv[nt]) * osz + res[(size_t)row * 256 + col];
        }
      }
  } else if (mode == 2) {
    uint16_t* C = (uint16_t*)args.C[z];
    #pragma unroll
    for (int mt = 0; mt < 4; ++mt)
      #pragma unroll
      for (int r = 0; r < 4; ++r) {
        const int row = m0 + wm + mt * 16 + 4 * g + r;
        const int bb = row >> 10, n = row & 1023;
        #pragma unroll
        for (int nt = 0; nt < 4; ++nt) {
          const int col = n0 + wn + nt * 16 + c;
          const int hh = col >> 5, d = col & 31;
          C[((size_t)(bb * 8 + hh) * 1024 + n) * 32 + d] =
              f2bf((acc[mt][nt][r] + bv[nt]) * osz);
        }
      }
  } else {
    uint16_t* C = (uint16_t*)args.C[z];
    #pragma unroll
    for (int mt = 0; mt < 4; ++mt)
      #pragma unroll
      for (int r = 0; r < 4; ++r) {
        const int row = m0 + wm + mt * 16 + 4 * g + r;
        const int bb = row >> 10, n = row & 1023;
        const int nn = (n & ~15) | phi4(n & 15);
        #pragma unroll
        for (int nt = 0; nt < 4; ++nt) {
          const int col = n0 + wn + nt * 16 + c;
          const int hh = col >> 5, d = col & 31;
          C[((size_t)(bb * 8 + hh) * 32 + d) * 1024 + nn] =
              f2bf((acc[mt][nt][r] + bv[nt]) * osz);
        }
      }
  }
}

// ---------------------------------------------------------------------------
// Fused masked flash attention, 32x32 MFMA, zero LDS, fixed-shift softmax.
// Lane (c=lane&31, hi=lane>>5) owns q-row c; S = mfma(K,Q, C=-12 splat);
// pv = v_exp(S) * bit; l-overflow guard rescales (never taken for sane data,
// exact when taken).  P packs feed PV directly (Vt phi-permuted at source).
// Q/K layout [b][h][n][32] -> coalesced, imm-offset-folded loads.
// ---------------------------------------------------------------------------
struct AttnArgs {
  const uint16_t* Q[4];
  const uint16_t* K[4];
  const uint16_t* Vt[4];
  const uint32_t* adjb[4];   // transposed [b][kw][q]
  uint16_t*       O[4];
};

__global__ __launch_bounds__(256) void attn_k(AttnArgs args) {
  const int bid = blockIdx.x;
  const int qt  = bid >> 7;           // 8 q-tiles per group
  const int grp = bid & 127;          // (branch,b,h) group -> same XCD
  const int bh = grp & 31, j = grp >> 5;
  const int b = bh >> 3, h = bh & 7;
  const int t = threadIdx.x, wid = t >> 6, lane = t & 63;
  const int c = lane & 31, hi = lane >> 5;
  const int qrow = qt * 128 + wid * 32 + c;

  const uint16_t* Qbh = args.Q[j] + (size_t)(b * 8 + h) * 32768;
  const uint16_t* Kbh = args.K[j] + (size_t)(b * 8 + h) * 32768;
  const uint16_t* Vp  = args.Vt[j] + ((size_t)(b * 8 + h) * 32 + c) * 1024 + hi * 8;
  const uint32_t* adjT = args.adjb[j] + (size_t)b * 32768 + qrow;

  const bf16x8 qf0 = *(const bf16x8*)&Qbh[qrow * 32 + hi * 8];
  const bf16x8 qf1 = *(const bf16x8*)&Qbh[qrow * 32 + 16 + hi * 8];

  f32x16 oacc = {};
  f32x16 cinit;
  #pragma unroll
  for (int r = 0; r < 16; ++r) cinit[r] = -12.0f;   // fixed softmax shift
  float l = 0.f;

  for (int k0 = 0; k0 < 1024; k0 += 32) {
    const uint32_t w = adjT[(size_t)(k0 >> 5) << 10] >> (hi * 4);
    const bf16x8 kf0 = *(const bf16x8*)&Kbh[(k0 + c) * 32 + hi * 8];
    const bf16x8 kf1 = *(const bf16x8*)&Kbh[(k0 + c) * 32 + 16 + hi * 8];
    const bf16x8 vf0 = *(const bf16x8*)(Vp + k0);        // issued early;
    const bf16x8 vf1 = *(const bf16x8*)(Vp + k0 + 16);   // used post-softmax

    f32x16 st = cinit;
    st = __builtin_amdgcn_mfma_f32_32x32x16_bf16(kf0, qf0, st, 0, 0, 0);
    st = __builtin_amdgcn_mfma_f32_32x32x16_bf16(kf1, qf1, st, 0, 0, 0);

    float s0 = 0.f, s1 = 0.f, s2 = 0.f, s3 = 0.f;
    #pragma unroll
    for (int r = 0; r < 16; ++r) {
      const int pos = (r & 3) + 8 * (r >> 2);   // bit pos (w pre-shifted by 4*hi)
      const float bitf = (float)((w >> pos) & 1u);
      const float pv = __builtin_amdgcn_exp2f(st[r]) * bitf;  // bare v_exp_f32
      st[r] = pv;
      if ((r & 3) == 0) s0 += pv; else if ((r & 3) == 1) s1 += pv;
      else if ((r & 3) == 2) s2 += pv; else s3 += pv;
    }
    l += (s0 + s1) + (s2 + s3);

    union PU { uint32_t u[4]; bf16x8 v; };
    PU p0, p1;
    p0.u[0] = packbf2(st[0],  st[1]);  p0.u[1] = packbf2(st[2],  st[3]);
    p0.u[2] = packbf2(st[4],  st[5]);  p0.u[3] = packbf2(st[6],  st[7]);
    p1.u[0] = packbf2(st[8],  st[9]);  p1.u[1] = packbf2(st[10], st[11]);
    p1.u[2] = packbf2(st[12], st[13]); p1.u[3] = packbf2(st[14], st[15]);

    oacc = __builtin_amdgcn_mfma_f32_32x32x16_bf16(vf0, p0.v, oacc, 0, 0, 0);
    oacc = __builtin_amdgcn_mfma_f32_32x32x16_bf16(vf1, p1.v, oacc, 0, 0, 0);

    if (__builtin_expect(__any(l > 1e18f), 0)) {       // overflow guard (cold)
      const float ds = 0x1p-64f;
      l *= ds;
      #pragma unroll
      for (int r = 0; r < 16; ++r) { oacc[r] *= ds; cinit[r] -= 64.0f; }
    }
  }

  l += __shfl_xor(l, 32, 64);
  const float inv = 1.0f / l;
  uint16_t* O = args.O[j];
  const size_t ob = (size_t)(b * 1024 + qrow) * 256 + h * 32 + 4 * hi;
  #pragma unroll
  for (int rq = 0; rq < 4; ++rq) {
    uint2 val;
    val.x = packbf2(oacc[4*rq+0] * inv, oacc[4*rq+1] * inv);
    val.y = packbf2(oacc[4*rq+2] * inv, oacc[4*rq+3] * inv);
    *(uint2*)&O[ob + 8 * rq] = val;
  }
}

// ---------------------------------------------------------------------------
// Fused LayerNorm(x0)+LayerNorm(x1) -> relu(sum) (+ optional input residual)
// Optionally writes a bf16 mirror (next layer's GEMM A input).
// ---------------------------------------------------------------------------
struct LnArgs {
  const float* x0; const float* x1;
  const float* g0; const float* be0;
  const float* g1; const float* be1;
  const float* addin;
  float* out;
  uint16_t* outbf;
};
struct LnBoth { LnArgs p[2]; };

__global__ __launch_bounds__(256) void ln_k(LnBoth args) {
  const LnArgs a = args.p[blockIdx.z];
  const int wid = threadIdx.x >> 6, lane = threadIdx.x & 63;
  const int row = blockIdx.x * 4 + wid;
  const size_t off = (size_t)row * 256 + lane * 4;

  const float4 x0 = *(const float4*)(a.x0 + off);
  const float4 x1 = *(const float4*)(a.x1 + off);
  float s0 = x0.x + x0.y + x0.z + x0.w;
  float s1 = x1.x + x1.y + x1.z + x1.w;
  #pragma unroll
  for (int s = 1; s < 64; s <<= 1) { s0 += __shfl_xor(s0, s, 64); s1 += __shfl_xor(s1, s, 64); }
  const float mu0 = s0 * (1.f / 256.f), mu1 = s1 * (1.f / 256.f);
  const float d0x = x0.x - mu0, d0y = x0.y - mu0, d0z = x0.z - mu0, d0w = x0.w - mu0;
  const float d1x = x1.x - mu1, d1y = x1.y - mu1, d1z = x1.z - mu1, d1w = x1.w - mu1;
  float v0 = d0x * d0x + d0y * d0y + d0z * d0z + d0w * d0w;
  float v1 = d1x * d1x + d1y * d1y + d1z * d1z + d1w * d1w;
  #pragma unroll
  for (int s = 1; s < 64; s <<= 1) { v0 += __shfl_xor(v0, s, 64); v1 += __shfl_xor(v1, s, 64); }
  const float r0 = rsqrtf(v0 * (1.f / 256.f) + 1e-5f);
  const float r1 = rsqrtf(v1 * (1.f / 256.f) + 1e-5f);

  const size_t po = (size_t)lane * 4;
  const float4 g0 = *(const float4*)(a.g0 + po), b0 = *(const float4*)(a.be0 + po);
  const float4 g1 = *(const float4*)(a.g1 + po), b1 = *(const float4*)(a.be1 + po);

  float4 y;
  y.x = fmaxf(d0x * r0 * g0.x + b0.x + d1x * r1 * g1.x + b1.x, 0.f);
  y.y = fmaxf(d0y * r0 * g0.y + b0.y + d1y * r1 * g1.y + b1.y, 0.f);
  y.z = fmaxf(d0z * r0 * g0.z + b0.z + d1z * r1 * g1.z + b1.z, 0.f);
  y.w = fmaxf(d0w * r0 * g0.w + b0.w + d1w * r1 * g1.w + b1.w, 0.f);
  if (a.addin) {
    const float4 ad = *(const float4*)(a.addin + off);
    y.x += ad.x; y.y += ad.y; y.z += ad.z; y.w += ad.w;
  }
  *(float4*)(a.out + off) = y;
  if (a.outbf) {
    uint2 vb;
    vb.x = packbf2(y.x, y.y); vb.y = packbf2(y.z, y.w);
    *(uint2*)(a.outbf + off) = vb;
  }
}

// ---------------------------------------------------------------------------
// Host launch
// ---------------------------------------------------------------------------
extern "C" void kernel_launch(void* const* d_in, const int* in_sizes, int n_in,
                              void* d_out, int out_size, void* d_ws, size_t ws_size,
                              hipStream_t stream) {
  (void)in_sizes; (void)n_in; (void)out_size; (void)ws_size;
  const float* h_a = (const float*)d_in[0];
  const float* h_b = (const float*)d_in[1];
  const float* bq  = (const float*)d_in[7];
  const float* bk  = (const float*)d_in[9];
  const float* bv  = (const float*)d_in[11];
  const float* bo  = (const float*)d_in[13];
  const float* lng = (const float*)d_in[14];
  const float* lnb = (const float*)d_in[15];

  // log2(e)/sqrt(dk): folds softmax scale + exp->exp2 into Q projection
  const float QSC = 1.4426950408889634f * 0.17677669529663687f;

  char* ws = (char*)d_ws;
  uint16_t* WT   = (uint16_t*)ws;                        // 0-4 MB
  uint32_t* ADJB = (uint32_t*)(ws + (4u  << 20));        // 4-6 MB (transposed)
  float*    hA   = (float*)   (ws + (6u  << 20));        // 6-10 MB
  float*    hB   = (float*)   (ws + (10u << 20));        // 10-14 MB
  uint16_t* hAbf = (uint16_t*)(ws + (14u << 20));        // 14-16 MB
  uint16_t* hBbf = (uint16_t*)(ws + (16u << 20));        // 16-18 MB
  uint16_t* Qb[4]; uint16_t* Kb[4]; uint16_t* Vtb[4]; uint16_t* ATb[4]; float* MO[4];
  for (int j = 0; j < 4; ++j) {
    Qb[j]  = (uint16_t*)(ws + (18u << 20) + (size_t)j * (2u << 20));  // 18-26
    Kb[j]  = (uint16_t*)(ws + (26u << 20) + (size_t)j * (2u << 20));  // 26-34
    MO[j]  = (float*)   (ws + (18u << 20) + (size_t)j * (4u << 20));  // 18-34 (over Qb/Kb, dead by then)
    Vtb[j] = (uint16_t*)(ws + (34u << 20) + (size_t)j * (2u << 20));  // 34-42
    ATb[j] = (uint16_t*)(ws + (42u << 20) + (size_t)j * (2u << 20));  // 42-50
  }

  wprep_k<<<dim3(4, 4, 32), 256, 0, stream>>>(
      (const float*)d_in[6], (const float*)d_in[8],
      (const float*)d_in[10], (const float*)d_in[12], WT);
  cvt_k<<<dim3(512, 2), 256, 0, stream>>>(h_a, h_b, hAbf, hBbf);
  {
    AdjArgs aa;
    for (int j = 0; j < 4; ++j) {
      aa.adj[j]  = (const int*)d_in[2 + j];
      aa.bits[j] = ADJB + (size_t)j * 131072;
    }
    adjbits_k<<<dim3(16384, 1, 4), 256, 0, stream>>>(aa);
  }

  for (int i = 0; i < 2; ++i) {
    const float* inA = (i == 0) ? h_a : hA;       // fp32 (residual for O-proj)
    const float* inB = (i == 0) ? h_b : hB;
    const float* qin[4]   = { inA, inB, inB, inA };   // a2a, b2b, a2b, b2a
    const uint16_t* qbf[4]  = { hAbf, hBbf, hBbf, hAbf };
    const uint16_t* kvbf[4] = { hAbf, hBbf, hAbf, hBbf };

    {
      GemmArgs ga = {};
      for (int j = 0; j < 4; ++j) {
        const int mm = i * 4 + j;
        ga.A[j]     = qbf[j];  ga.W[j]     = WT + 0 * 524288 + (size_t)mm * 65536;
        ga.bias[j]  = bq + mm * 256; ga.C[j] = Qb[j];  ga.os[j] = QSC;  ga.mode[j] = 2;
        ga.A[4+j]   = kvbf[j]; ga.W[4+j]   = WT + 1 * 524288 + (size_t)mm * 65536;
        ga.bias[4+j]= bk + mm * 256; ga.C[4+j] = Kb[j]; ga.os[4+j] = 1.0f; ga.mode[4+j] = 2;
        ga.A[8+j]   = kvbf[j]; ga.W[8+j]   = WT + 2 * 524288 + (size_t)mm * 65536;
        ga.bias[8+j]= bv + mm * 256; ga.C[8+j] = Vtb[j]; ga.os[8+j] = 1.0f; ga.mode[8+j] = 3;
      }
      gemm_k<<<dim3(2, 32, 12), 256, 0, stream>>>(ga);
    }
    {
      AttnArgs at;
      for (int j = 0; j < 4; ++j) {
        at.Q[j] = Qb[j]; at.K[j] = Kb[j]; at.Vt[j] = Vtb[j];
        at.adjb[j] = ADJB + (size_t)j * 131072; at.O[j] = ATb[j];
      }
      attn_k<<<dim3(1024, 1, 1), 256, 0, stream>>>(at);
    }
    {
      GemmArgs go = {};
      for (int j = 0; j < 4; ++j) {
        const int mm = i * 4 + j;
        go.A[j] = ATb[j]; go.W[j] = WT + 3 * 524288 + (size_t)mm * 65536;
        go.bias[j] = bo + mm * 256; go.res[j] = qin[j]; go.C[j] = MO[j];
        go.os[j] = 1.0f; go.mode[j] = 1;
      }
      gemm_k<<<dim3(2, 32, 4), 256, 0, stream>>>(go);
    }
    {
      LnBoth lb;
      float* outA = (i == 1) ? (float*)d_out : hA;
      float* outB = (i == 1) ? ((float*)d_out + 1048576) : hB;
      const float* addA = (i == 1) ? h_a : nullptr;
      const float* addB = (i == 1) ? h_b : nullptr;
      uint16_t* mbA = (i == 0) ? hAbf : nullptr;   // bf16 mirror for next layer
      uint16_t* mbB = (i == 0) ? hBbf : nullptr;
      lb.p[0] = { MO[0], MO[3],
                  lng + (i * 4 + 0) * 256, lnb + (i * 4 + 0) * 256,
                  lng + (i * 4 + 3) * 256, lnb + (i * 4 + 3) * 256,
                  addA, outA, mbA };
      lb.p[1] = { MO[1], MO[2],
                  lng + (i * 4 + 1) * 256, lnb + (i * 4 + 1) * 256,
                  lng + (i * 4 + 2) * 256, lnb + (i * 4 + 2) * 256,
                  addB, outB, mbB };
      ln_k<<<dim3(1024, 1, 2), 256, 0, stream>>>(lb);
    }
  }
}